// Round 1
// baseline (1096.252 us; speedup 1.0000x reference)
//
#include <hip/hip_runtime.h>
#include <math.h>

// Problem constants
constexpr int kN = 25000;
constexpr int kE = 400000;
constexpr int kNodeIn = 128;
constexpr int kEdgeIn = 32;
constexpr int kHid = 64;
constexpr int kHeads = 4;
constexpr int kHC = 256;        // HEADS*HID
constexpr int kIntents = 12;

// ---------------- workspace layout (all 256B aligned) ----------------
constexpr size_t OFF_EAPART = 0;                       // 1024*32 f32 = 131072
constexpr size_t OFF_EAMEAN = 131072;                  // 32 f32 (pad 256)
constexpr size_t OFF_EPLOOP = 131328;                  // 256 f32 = 1024
constexpr size_t OFF_COUNTS = 132352;                  // N i32 -> 100096
constexpr size_t OFF_OFFS   = 232448;                  // N+1 i32 -> 100096
constexpr size_t OFF_CURSOR = 332544;                  // N i32 -> 100096
constexpr size_t OFF_CSRSRC = 432640;                  // (E+N) i32 -> 1700096
constexpr size_t OFF_CSREID = 2132736;                 // (E+N) i32 -> 1700096
constexpr size_t OFF_HA     = 3832832;                 // N*64 f32 = 6400000
constexpr size_t OFF_HB     = 10232832;                // N*64 f32
constexpr size_t OFF_XL     = 16632832;                // N*256 f32 = 25600000
constexpr size_t OFF_XR     = 42232832;                // N*256 f32
// total ~67.8 MB

// ---------------- edge_attr column mean ----------------
__global__ __launch_bounds__(256) void ea_colsum_part(const float* __restrict__ ea,
                                                      float* __restrict__ part)
{
    __shared__ float lds[256];
    const int tid = threadIdx.x;
    const int k = tid & 31, g = tid >> 5;
    float acc = 0.f;
    for (int r = blockIdx.x * 8 + g; r < kE; r += gridDim.x * 8)
        acc += ea[(size_t)r * 32 + k];
    lds[tid] = acc; __syncthreads();
    if (tid < 128) lds[tid] += lds[tid + 128]; __syncthreads();
    if (tid < 64)  lds[tid] += lds[tid + 64];  __syncthreads();
    if (tid < 32)  part[blockIdx.x * 32 + k] = lds[tid] + lds[tid + 32];
}

__global__ __launch_bounds__(256) void ea_colsum_final(const float* __restrict__ part,
                                                       float* __restrict__ ea_mean)
{
    __shared__ float lds[256];
    const int tid = threadIdx.x;
    const int k = tid & 31, g = tid >> 5;
    float acc = 0.f;
    for (int p = g; p < 1024; p += 8) acc += part[p * 32 + k];
    lds[tid] = acc; __syncthreads();
    if (tid < 128) lds[tid] += lds[tid + 128]; __syncthreads();
    if (tid < 64)  lds[tid] += lds[tid + 64];  __syncthreads();
    if (tid < 32)  ea_mean[k] = (lds[tid] + lds[tid + 32]) * (1.0f / (float)kE);
}

// ep_loop[tid] = ea_mean @ We  (self-loop edge projection, 256 outputs)
__global__ __launch_bounds__(256) void ep_loop_kernel(const float* __restrict__ eam,
                                                      const float* __restrict__ We,
                                                      float* __restrict__ epl)
{
    const int tid = threadIdx.x;
    float acc = 0.f;
#pragma unroll
    for (int kk = 0; kk < 32; kk++) acc += eam[kk] * We[kk * 256 + tid];
    epl[tid] = acc;
}

// ---------------- CSR build ----------------
__global__ __launch_bounds__(256) void init_counts(int* __restrict__ counts)
{
    int i = blockIdx.x * 256 + threadIdx.x;
    if (i < kN) counts[i] = 1;   // self-loop pre-counted
}

__global__ __launch_bounds__(256) void count_edges(const int* __restrict__ ei,
                                                   int* __restrict__ counts)
{
    int e = blockIdx.x * 256 + threadIdx.x;
    if (e < kE) atomicAdd(&counts[ei[kE + e]], 1);
}

__global__ __launch_bounds__(1024) void scan_kernel(const int* __restrict__ counts,
                                                    int* __restrict__ offsets,
                                                    int* __restrict__ cursor)
{
    __shared__ int lds[1024];
    const int tid = threadIdx.x;
    const int base = tid * 25;
    int local = 0;
#pragma unroll 5
    for (int i = 0; i < 25; i++) {
        int idx = base + i;
        if (idx < kN) local += counts[idx];
    }
    lds[tid] = local; __syncthreads();
    for (int d = 1; d < 1024; d <<= 1) {
        int t = (tid >= d) ? lds[tid - d] : 0;
        __syncthreads();
        lds[tid] += t;
        __syncthreads();
    }
    int run = lds[tid] - local;   // exclusive prefix
    for (int i = 0; i < 25; i++) {
        int idx = base + i;
        if (idx < kN) {
            offsets[idx] = run;
            cursor[idx]  = run;
            run += counts[idx];
        }
    }
    if (tid == 1023) offsets[kN] = lds[1023];
}

__global__ __launch_bounds__(256) void scatter_kernel(const int* __restrict__ ei,
                                                      int* __restrict__ cursor,
                                                      int* __restrict__ csr_src,
                                                      int* __restrict__ csr_eid)
{
    int gid = blockIdx.x * 256 + threadIdx.x;
    if (gid < kE) {
        int s = ei[gid];
        int d = ei[kE + gid];
        int p = atomicAdd(&cursor[d], 1);
        csr_src[p] = s;
        csr_eid[p] = gid;
    } else if (gid < kE + kN) {
        int n = gid - kE;
        int p = atomicAdd(&cursor[n], 1);
        csr_src[p] = n;
        csr_eid[p] = kE;   // sentinel: self-loop
    }
}

// ---------------- small dense GEMM: out[M,KO] = A[M,KI]@W[KI,KO] + b ----------------
template<int KI, int KO, int RPB>
__global__ __launch_bounds__(256) void gemm_bias(const float* __restrict__ A,
                                                 const float* __restrict__ W,
                                                 const float* __restrict__ bias,
                                                 float* __restrict__ out, int M)
{
    constexpr int CG  = 256 / KO;   // column groups
    constexpr int RPT = RPB / CG;   // rows per thread
    __shared__ __align__(16) float a_lds[RPB * KI];
    const int tid = threadIdx.x;
    const int col = tid % KO;
    const int g   = tid / KO;
    const int row0 = blockIdx.x * RPB;

    // stage A tile (rows are contiguous)
    const float4* Ab = (const float4*)(A + (size_t)row0 * KI);
    float4* L4 = (float4*)a_lds;
    constexpr int ELEM4 = RPB * KI / 4;
    for (int i = tid; i < ELEM4; i += 256) {
        int r = (i * 4) / KI;
        float4 v = make_float4(0.f, 0.f, 0.f, 0.f);
        if (row0 + r < M) v = Ab[i];
        L4[i] = v;
    }
    __syncthreads();

    float acc[RPT];
#pragma unroll
    for (int r = 0; r < RPT; r++) acc[r] = 0.f;
    const float* arow = a_lds + (size_t)(g * RPT) * KI;
    for (int k0 = 0; k0 < KI; k0 += 4) {
        float w0 = W[(k0 + 0) * KO + col];
        float w1 = W[(k0 + 1) * KO + col];
        float w2 = W[(k0 + 2) * KO + col];
        float w3 = W[(k0 + 3) * KO + col];
#pragma unroll
        for (int r = 0; r < RPT; r++) {
            const float4 a = *(const float4*)(arow + r * KI + k0);
            acc[r] += a.x * w0 + a.y * w1 + a.z * w2 + a.w * w3;
        }
    }
    const float bv = bias[col];
#pragma unroll
    for (int r = 0; r < RPT; r++) {
        int row = row0 + g * RPT + r;
        if (row < M) out[(size_t)row * KO + col] = acc[r] + bv;
    }
}

// ---------------- fused GATv2 layer: per-destination-node online softmax + aggregate ----------------
// block = 256 threads; wave w = head w, lane = channel. One pass over incoming edges.
__global__ __launch_bounds__(256) void gat_node_kernel(
    const float* __restrict__ xl, const float* __restrict__ xr,
    const float* __restrict__ ea, const float* __restrict__ We,
    const float* __restrict__ att, const float* __restrict__ epl,
    const float* __restrict__ gbias,
    const int* __restrict__ offsets, const int* __restrict__ csr_src,
    const int* __restrict__ csr_eid, float* __restrict__ h_out)
{
    __shared__ __align__(16) float ea_lds[32 * 32];
    __shared__ int s_src[32];
    __shared__ int s_eid[32];
    __shared__ float red[256];
    const int tid = threadIdx.x;

    // per-thread column of We (32 regs) + att + self-loop ep
    float we[32];
#pragma unroll
    for (int kk = 0; kk < 32; kk++) we[kk] = We[kk * 256 + tid];
    const float att_r = att[tid];
    const float epl_r = epl[tid];

    for (int n = blockIdx.x; n < kN; n += gridDim.x) {
        const int o0 = offsets[n], o1 = offsets[n + 1];
        const float xr_r = xr[(size_t)n * 256 + tid];
        float mx = -3.4e38f, den = 0.f, acc = 0.f;

        for (int b0 = o0; b0 < o1; b0 += 32) {
            const int cnt = min(32, o1 - b0);
            __syncthreads();
            if (tid < cnt) {
                s_src[tid] = csr_src[b0 + tid];
                s_eid[tid] = csr_eid[b0 + tid];
            }
            __syncthreads();
            {   // stage edge_attr rows: 8 lanes (float4 each) per edge
                int j = tid >> 3, q = tid & 7;
                if (j < cnt) {
                    int eid = s_eid[j];
                    if (eid < kE)
                        ((float4*)ea_lds)[j * 8 + q] = ((const float4*)ea)[(size_t)eid * 8 + q];
                }
            }
            __syncthreads();

            for (int i = 0; i < cnt; i++) {
                const int s   = s_src[i];
                const int eid = s_eid[i];
                float ep;
                if (eid < kE) {
                    ep = 0.f;
                    const float4* av = (const float4*)(ea_lds + i * 32);
#pragma unroll
                    for (int q = 0; q < 8; q++) {
                        float4 a = av[q];
                        ep += a.x * we[4 * q + 0];
                        ep += a.y * we[4 * q + 1];
                        ep += a.z * we[4 * q + 2];
                        ep += a.w * we[4 * q + 3];
                    }
                } else {
                    ep = epl_r;
                }
                const float xls = xl[(size_t)s * 256 + tid];
                float v = xls + xr_r + ep;
                v = (v > 0.f) ? v : 0.2f * v;                 // leaky_relu 0.2
                float c = att_r * v;
#pragma unroll
                for (int d = 1; d < 64; d <<= 1) c += __shfl_xor(c, d);  // logit, all lanes
                const float nm = fmaxf(mx, c);
                const float sc = __expf(mx - nm);
                const float pe = __expf(c - nm);
                den = den * sc + pe;
                acc = acc * sc + pe * xls;
                mx = nm;
            }
        }
        __syncthreads();
        red[tid] = acc / den;
        __syncthreads();
        if (tid < 64) {
            float sres = red[tid] + red[tid + 64] + red[tid + 128] + red[tid + 192];
            h_out[(size_t)n * 64 + tid] = fmaxf(0.25f * sres + gbias[tid], 0.f);
        }
    }
}

// ---------------- final edge heads: intent logits + importance ----------------
__global__ __launch_bounds__(256) void edge_head(
    const float* __restrict__ h, const int* __restrict__ ei,
    const float* __restrict__ ea, const float* __restrict__ intW,
    const float* __restrict__ intb, const float* __restrict__ impW,
    const float* __restrict__ impb, float* __restrict__ out)
{
    __shared__ __align__(16) float rep[16 * 164];
    __shared__ __align__(16) float W13[13 * 164];
    __shared__ int s_src[16], s_dst[16];
    const int tid = threadIdx.x;
    const int e0 = blockIdx.x * 16;

    for (int i = tid; i < 13 * 160; i += 256) {
        int k = i / 13, c = i % 13;
        W13[c * 164 + k] = (c < 12) ? intW[k * 12 + c] : impW[k];
    }
    if (tid < 16) {
        s_src[tid] = ei[e0 + tid];
        s_dst[tid] = ei[kE + e0 + tid];
    }
    __syncthreads();

    for (int i = tid; i < 16 * 160; i += 256) {
        int j = i / 160, k = i % 160;
        float v;
        if (k < 64)       v = h[(size_t)s_src[j] * 64 + k];
        else if (k < 128) v = h[(size_t)s_dst[j] * 64 + (k - 64)];
        else              v = ea[(size_t)(e0 + j) * 32 + (k - 128)];
        rep[j * 164 + k] = fmaxf(v, 0.f);   // relu(concat)
    }
    __syncthreads();

    if (tid < 16 * 13) {
        int j = tid / 13, c = tid % 13;
        const float4* rp = (const float4*)(rep + j * 164);
        const float4* wp = (const float4*)(W13 + c * 164);
        float acc = 0.f;
#pragma unroll 8
        for (int q = 0; q < 40; q++) {
            float4 a = rp[q], w = wp[q];
            acc += a.x * w.x + a.y * w.y + a.z * w.z + a.w * w.w;
        }
        int eg = e0 + j;
        if (c < 12) {
            out[(size_t)eg * 12 + c] = acc + intb[c];
        } else {
            float z = acc + impb[0];
            out[(size_t)kE * 12 + eg] = 1.f / (1.f + __expf(-z));
        }
    }
}

// ---------------- launch ----------------
extern "C" void kernel_launch(void* const* d_in, const int* in_sizes, int n_in,
                              void* d_out, int out_size, void* d_ws, size_t ws_size,
                              hipStream_t stream)
{
    (void)in_sizes; (void)n_in; (void)out_size; (void)ws_size;

    const float* x      = (const float*)d_in[0];
    const int*   ei     = (const int*)d_in[1];
    const float* ea     = (const float*)d_in[2];
    const float* emb_W  = (const float*)d_in[3];
    const float* emb_b  = (const float*)d_in[4];
    const float* g1_Wl  = (const float*)d_in[5];
    const float* g1_bl  = (const float*)d_in[6];
    const float* g1_Wr  = (const float*)d_in[7];
    const float* g1_br  = (const float*)d_in[8];
    const float* g1_We  = (const float*)d_in[9];
    const float* g1_att = (const float*)d_in[10];
    const float* g1_bias= (const float*)d_in[11];
    const float* g2_Wl  = (const float*)d_in[12];
    const float* g2_bl  = (const float*)d_in[13];
    const float* g2_Wr  = (const float*)d_in[14];
    const float* g2_br  = (const float*)d_in[15];
    const float* g2_We  = (const float*)d_in[16];
    const float* g2_att = (const float*)d_in[17];
    const float* g2_bias= (const float*)d_in[18];
    const float* int_W  = (const float*)d_in[19];
    const float* int_b  = (const float*)d_in[20];
    const float* imp_W  = (const float*)d_in[21];
    const float* imp_b  = (const float*)d_in[22];

    char* ws = (char*)d_ws;
    float* eapart  = (float*)(ws + OFF_EAPART);
    float* eamean  = (float*)(ws + OFF_EAMEAN);
    float* eploop  = (float*)(ws + OFF_EPLOOP);
    int*   counts  = (int*)  (ws + OFF_COUNTS);
    int*   offs    = (int*)  (ws + OFF_OFFS);
    int*   cursor  = (int*)  (ws + OFF_CURSOR);
    int*   csrsrc  = (int*)  (ws + OFF_CSRSRC);
    int*   csreid  = (int*)  (ws + OFF_CSREID);
    float* h_a     = (float*)(ws + OFF_HA);
    float* h_b     = (float*)(ws + OFF_HB);
    float* xl      = (float*)(ws + OFF_XL);
    float* xr      = (float*)(ws + OFF_XR);
    float* outp    = (float*)d_out;

    // edge_attr mean
    ea_colsum_part<<<1024, 256, 0, stream>>>(ea, eapart);
    ea_colsum_final<<<1, 256, 0, stream>>>(eapart, eamean);

    // CSR by destination (self-loops included)
    init_counts<<<(kN + 255) / 256, 256, 0, stream>>>(counts);
    count_edges<<<(kE + 255) / 256, 256, 0, stream>>>(ei, counts);
    scan_kernel<<<1, 1024, 0, stream>>>(counts, offs, cursor);
    scatter_kernel<<<(kE + kN + 255) / 256, 256, 0, stream>>>(ei, cursor, csrsrc, csreid);

    // node embedding
    gemm_bias<128, 64, 32><<<(kN + 31) / 32, 256, 0, stream>>>(x, emb_W, emb_b, h_a, kN);

    // ---- GAT layer 1 ----
    gemm_bias<64, 256, 32><<<(kN + 31) / 32, 256, 0, stream>>>(h_a, g1_Wl, g1_bl, xl, kN);
    gemm_bias<64, 256, 32><<<(kN + 31) / 32, 256, 0, stream>>>(h_a, g1_Wr, g1_br, xr, kN);
    ep_loop_kernel<<<1, 256, 0, stream>>>(eamean, g1_We, eploop);
    gat_node_kernel<<<4096, 256, 0, stream>>>(xl, xr, ea, g1_We, g1_att, eploop, g1_bias,
                                              offs, csrsrc, csreid, h_b);

    // ---- GAT layer 2 ----
    gemm_bias<64, 256, 32><<<(kN + 31) / 32, 256, 0, stream>>>(h_b, g2_Wl, g2_bl, xl, kN);
    gemm_bias<64, 256, 32><<<(kN + 31) / 32, 256, 0, stream>>>(h_b, g2_Wr, g2_br, xr, kN);
    ep_loop_kernel<<<1, 256, 0, stream>>>(eamean, g2_We, eploop);
    gat_node_kernel<<<4096, 256, 0, stream>>>(xl, xr, ea, g2_We, g2_att, eploop, g2_bias,
                                              offs, csrsrc, csreid, h_a);

    // ---- edge heads ----
    edge_head<<<kE / 16, 256, 0, stream>>>(h_a, ei, ea, int_W, int_b, imp_W, imp_b, outp);
}

// Round 2
// 959.936 us; speedup vs baseline: 1.1420x; 1.1420x over previous
//
#include <hip/hip_runtime.h>
#include <math.h>

// Problem constants
constexpr int kN = 25000;
constexpr int kE = 400000;
constexpr int kNodeIn = 128;
constexpr int kEdgeIn = 32;
constexpr int kHid = 64;
constexpr int kHeads = 4;
constexpr int kHC = 256;        // HEADS*HID
constexpr int kIntents = 12;

// ---------------- workspace layout (all 256B aligned) ----------------
constexpr size_t OFF_EAPART = 0;                       // 1024*32 f32 = 131072
constexpr size_t OFF_EAMEAN = 131072;                  // 32 f32 (pad 256)
constexpr size_t OFF_EPLOOP = 131328;                  // 256 f32 = 1024
constexpr size_t OFF_COUNTS = 132352;                  // N i32 -> 100096
constexpr size_t OFF_OFFS   = 232448;                  // N+1 i32 -> 100096
constexpr size_t OFF_CURSOR = 332544;                  // N i32 -> 100096
constexpr size_t OFF_CSRSRC = 432640;                  // (E+N) i32 -> 1700096
constexpr size_t OFF_CSREID = 2132736;                 // (E+N) i32 -> 1700096
constexpr size_t OFF_HA     = 3832832;                 // N*64 f32 = 6400000
constexpr size_t OFF_HB     = 10232832;                // N*64 f32
constexpr size_t OFF_XL     = 16632832;                // N*256 f32 = 25600000
constexpr size_t OFF_XR     = 42232832;                // N*256 f32
// total ~67.8 MB

// ---------------- edge_attr column mean ----------------
__global__ __launch_bounds__(256) void ea_colsum_part(const float* __restrict__ ea,
                                                      float* __restrict__ part)
{
    __shared__ float lds[256];
    const int tid = threadIdx.x;
    const int k = tid & 31, g = tid >> 5;
    float acc = 0.f;
    for (int r = blockIdx.x * 8 + g; r < kE; r += gridDim.x * 8)
        acc += ea[(size_t)r * 32 + k];
    lds[tid] = acc; __syncthreads();
    if (tid < 128) lds[tid] += lds[tid + 128]; __syncthreads();
    if (tid < 64)  lds[tid] += lds[tid + 64];  __syncthreads();
    if (tid < 32)  part[blockIdx.x * 32 + k] = lds[tid] + lds[tid + 32];
}

__global__ __launch_bounds__(256) void ea_colsum_final(const float* __restrict__ part,
                                                       float* __restrict__ ea_mean)
{
    __shared__ float lds[256];
    const int tid = threadIdx.x;
    const int k = tid & 31, g = tid >> 5;
    float acc = 0.f;
    for (int p = g; p < 1024; p += 8) acc += part[p * 32 + k];
    lds[tid] = acc; __syncthreads();
    if (tid < 128) lds[tid] += lds[tid + 128]; __syncthreads();
    if (tid < 64)  lds[tid] += lds[tid + 64];  __syncthreads();
    if (tid < 32)  ea_mean[k] = (lds[tid] + lds[tid + 32]) * (1.0f / (float)kE);
}

// ep_loop[tid] = ea_mean @ We  (self-loop edge projection, 256 outputs)
__global__ __launch_bounds__(256) void ep_loop_kernel(const float* __restrict__ eam,
                                                      const float* __restrict__ We,
                                                      float* __restrict__ epl)
{
    const int tid = threadIdx.x;
    float acc = 0.f;
#pragma unroll
    for (int kk = 0; kk < 32; kk++) acc += eam[kk] * We[kk * 256 + tid];
    epl[tid] = acc;
}

// ---------------- CSR build ----------------
__global__ __launch_bounds__(256) void init_counts(int* __restrict__ counts)
{
    int i = blockIdx.x * 256 + threadIdx.x;
    if (i < kN) counts[i] = 1;   // self-loop pre-counted
}

__global__ __launch_bounds__(256) void count_edges(const int* __restrict__ ei,
                                                   int* __restrict__ counts)
{
    int e = blockIdx.x * 256 + threadIdx.x;
    if (e < kE) atomicAdd(&counts[ei[kE + e]], 1);
}

__global__ __launch_bounds__(1024) void scan_kernel(const int* __restrict__ counts,
                                                    int* __restrict__ offsets,
                                                    int* __restrict__ cursor)
{
    __shared__ int lds[1024];
    const int tid = threadIdx.x;
    const int base = tid * 25;
    int local = 0;
#pragma unroll 5
    for (int i = 0; i < 25; i++) {
        int idx = base + i;
        if (idx < kN) local += counts[idx];
    }
    lds[tid] = local; __syncthreads();
    for (int d = 1; d < 1024; d <<= 1) {
        int t = (tid >= d) ? lds[tid - d] : 0;
        __syncthreads();
        lds[tid] += t;
        __syncthreads();
    }
    int run = lds[tid] - local;   // exclusive prefix
    for (int i = 0; i < 25; i++) {
        int idx = base + i;
        if (idx < kN) {
            offsets[idx] = run;
            cursor[idx]  = run;
            run += counts[idx];
        }
    }
    if (tid == 1023) offsets[kN] = lds[1023];
}

__global__ __launch_bounds__(256) void scatter_kernel(const int* __restrict__ ei,
                                                      int* __restrict__ cursor,
                                                      int* __restrict__ csr_src,
                                                      int* __restrict__ csr_eid)
{
    int gid = blockIdx.x * 256 + threadIdx.x;
    if (gid < kE) {
        int s = ei[gid];
        int d = ei[kE + gid];
        int p = atomicAdd(&cursor[d], 1);
        csr_src[p] = s;
        csr_eid[p] = gid;
    } else if (gid < kE + kN) {
        int n = gid - kE;
        int p = atomicAdd(&cursor[n], 1);
        csr_src[p] = n;
        csr_eid[p] = kE;   // sentinel: self-loop
    }
}

// ---------------- small dense GEMM: out[M,KO] = A[M,KI]@W[KI,KO] + b ----------------
template<int KI, int KO, int RPB>
__global__ __launch_bounds__(256) void gemm_bias(const float* __restrict__ A,
                                                 const float* __restrict__ W,
                                                 const float* __restrict__ bias,
                                                 float* __restrict__ out, int M)
{
    constexpr int CG  = 256 / KO;   // column groups
    constexpr int RPT = RPB / CG;   // rows per thread
    __shared__ __align__(16) float a_lds[RPB * KI];
    const int tid = threadIdx.x;
    const int col = tid % KO;
    const int g   = tid / KO;
    const int row0 = blockIdx.x * RPB;

    // stage A tile (rows are contiguous)
    const float4* Ab = (const float4*)(A + (size_t)row0 * KI);
    float4* L4 = (float4*)a_lds;
    constexpr int ELEM4 = RPB * KI / 4;
    for (int i = tid; i < ELEM4; i += 256) {
        int r = (i * 4) / KI;
        float4 v = make_float4(0.f, 0.f, 0.f, 0.f);
        if (row0 + r < M) v = Ab[i];
        L4[i] = v;
    }
    __syncthreads();

    float acc[RPT];
#pragma unroll
    for (int r = 0; r < RPT; r++) acc[r] = 0.f;
    const float* arow = a_lds + (size_t)(g * RPT) * KI;
    for (int k0 = 0; k0 < KI; k0 += 4) {
        float w0 = W[(k0 + 0) * KO + col];
        float w1 = W[(k0 + 1) * KO + col];
        float w2 = W[(k0 + 2) * KO + col];
        float w3 = W[(k0 + 3) * KO + col];
#pragma unroll
        for (int r = 0; r < RPT; r++) {
            const float4 a = *(const float4*)(arow + r * KI + k0);
            acc[r] += a.x * w0 + a.y * w1 + a.z * w2 + a.w * w3;
        }
    }
    const float bv = bias[col];
#pragma unroll
    for (int r = 0; r < RPT; r++) {
        int row = row0 + g * RPT + r;
        if (row < M) out[(size_t)row * KO + col] = acc[r] + bv;
    }
}

// ---------------- fused GATv2 layer: per-destination-node online softmax + aggregate ----------------
// block = 256 threads; wave w = head w, lane = channel. One pass over incoming edges.
// Round 1: 4-edge batching — interleave 4 independent shuffle-reduce chains and
// amortize the serial online-softmax update 4x (was latency-bound at VALUBusy=60%).
__global__ __launch_bounds__(256) void gat_node_kernel(
    const float* __restrict__ xl, const float* __restrict__ xr,
    const float* __restrict__ ea, const float* __restrict__ We,
    const float* __restrict__ att, const float* __restrict__ epl,
    const float* __restrict__ gbias,
    const int* __restrict__ offsets, const int* __restrict__ csr_src,
    const int* __restrict__ csr_eid, float* __restrict__ h_out)
{
    __shared__ __align__(16) float ea_lds[32 * 32];
    __shared__ int s_src[32];
    __shared__ int s_eid[32];
    __shared__ float red[256];
    const int tid = threadIdx.x;

    // per-thread column of We (32 regs) + att + self-loop ep
    float we[32];
#pragma unroll
    for (int kk = 0; kk < 32; kk++) we[kk] = We[kk * 256 + tid];
    const float att_r = att[tid];
    const float epl_r = epl[tid];

    for (int n = blockIdx.x; n < kN; n += gridDim.x) {
        const int o0 = offsets[n], o1 = offsets[n + 1];
        const float xr_r = xr[(size_t)n * 256 + tid];
        float mx = -3.4e38f, den = 0.f, acc = 0.f;

        for (int b0 = o0; b0 < o1; b0 += 32) {
            const int cnt = min(32, o1 - b0);
            __syncthreads();
            if (tid < cnt) {
                s_src[tid] = csr_src[b0 + tid];
                s_eid[tid] = csr_eid[b0 + tid];
            }
            __syncthreads();
            {   // stage edge_attr rows: 8 lanes (float4 each) per edge
                int j = tid >> 3, q = tid & 7;
                if (j < cnt) {
                    int eid = s_eid[j];
                    if (eid < kE)
                        ((float4*)ea_lds)[j * 8 + q] = ((const float4*)ea)[(size_t)eid * 8 + q];
                }
            }
            __syncthreads();

            for (int i = 0; i < cnt; i += 4) {
                const int valid = min(4, cnt - i);
                float c[4], xls[4];
#pragma unroll
                for (int u = 0; u < 4; u++) {
                    c[u] = 0.f; xls[u] = 0.f;
                    if (u < valid) {
                        const int s   = s_src[i + u];
                        const int eid = s_eid[i + u];
                        xls[u] = xl[(size_t)s * 256 + tid];      // 4 independent gathers in flight
                        float ep;
                        if (eid < kE) {
                            ep = 0.f;
                            const float4* av = (const float4*)(ea_lds + (i + u) * 32);
#pragma unroll
                            for (int q = 0; q < 8; q++) {
                                float4 a = av[q];
                                ep += a.x * we[4 * q + 0];
                                ep += a.y * we[4 * q + 1];
                                ep += a.z * we[4 * q + 2];
                                ep += a.w * we[4 * q + 3];
                            }
                        } else {
                            ep = epl_r;
                        }
                        float v = xls[u] + xr_r + ep;
                        v = (v > 0.f) ? v : 0.2f * v;            // leaky_relu 0.2
                        c[u] = att_r * v;
                    }
                }
                // 4 interleaved butterfly chains — independent, pipeline the ds ops
#pragma unroll
                for (int d = 1; d < 64; d <<= 1) {
#pragma unroll
                    for (int u = 0; u < 4; u++) c[u] += __shfl_xor(c[u], d);
                }
                // single online-softmax update for the whole batch
                float bm = -3.4e38f;
#pragma unroll
                for (int u = 0; u < 4; u++) if (u < valid) bm = fmaxf(bm, c[u]);
                const float nm = fmaxf(mx, bm);
                const float sc = __expf(mx - nm);
                float pe[4];
#pragma unroll
                for (int u = 0; u < 4; u++)
                    pe[u] = (u < valid) ? __expf(c[u] - nm) : 0.f;
                den = den * sc + ((pe[0] + pe[1]) + (pe[2] + pe[3]));
                acc = acc * sc + (pe[0] * xls[0] + pe[1] * xls[1])
                               + (pe[2] * xls[2] + pe[3] * xls[3]);
                mx = nm;
            }
        }
        __syncthreads();
        red[tid] = acc / den;
        __syncthreads();
        if (tid < 64) {
            float sres = red[tid] + red[tid + 64] + red[tid + 128] + red[tid + 192];
            h_out[(size_t)n * 64 + tid] = fmaxf(0.25f * sres + gbias[tid], 0.f);
        }
    }
}

// ---------------- final edge heads: intent logits + importance ----------------
__global__ __launch_bounds__(256) void edge_head(
    const float* __restrict__ h, const int* __restrict__ ei,
    const float* __restrict__ ea, const float* __restrict__ intW,
    const float* __restrict__ intb, const float* __restrict__ impW,
    const float* __restrict__ impb, float* __restrict__ out)
{
    __shared__ __align__(16) float rep[16 * 164];
    __shared__ __align__(16) float W13[13 * 164];
    __shared__ int s_src[16], s_dst[16];
    const int tid = threadIdx.x;
    const int e0 = blockIdx.x * 16;

    for (int i = tid; i < 13 * 160; i += 256) {
        int k = i / 13, c = i % 13;
        W13[c * 164 + k] = (c < 12) ? intW[k * 12 + c] : impW[k];
    }
    if (tid < 16) {
        s_src[tid] = ei[e0 + tid];
        s_dst[tid] = ei[kE + e0 + tid];
    }
    __syncthreads();

    for (int i = tid; i < 16 * 160; i += 256) {
        int j = i / 160, k = i % 160;
        float v;
        if (k < 64)       v = h[(size_t)s_src[j] * 64 + k];
        else if (k < 128) v = h[(size_t)s_dst[j] * 64 + (k - 64)];
        else              v = ea[(size_t)(e0 + j) * 32 + (k - 128)];
        rep[j * 164 + k] = fmaxf(v, 0.f);   // relu(concat)
    }
    __syncthreads();

    if (tid < 16 * 13) {
        int j = tid / 13, c = tid % 13;
        const float4* rp = (const float4*)(rep + j * 164);
        const float4* wp = (const float4*)(W13 + c * 164);
        float acc = 0.f;
#pragma unroll 8
        for (int q = 0; q < 40; q++) {
            float4 a = rp[q], w = wp[q];
            acc += a.x * w.x + a.y * w.y + a.z * w.z + a.w * w.w;
        }
        int eg = e0 + j;
        if (c < 12) {
            out[(size_t)eg * 12 + c] = acc + intb[c];
        } else {
            float z = acc + impb[0];
            out[(size_t)kE * 12 + eg] = 1.f / (1.f + __expf(-z));
        }
    }
}

// ---------------- launch ----------------
extern "C" void kernel_launch(void* const* d_in, const int* in_sizes, int n_in,
                              void* d_out, int out_size, void* d_ws, size_t ws_size,
                              hipStream_t stream)
{
    (void)in_sizes; (void)n_in; (void)out_size; (void)ws_size;

    const float* x      = (const float*)d_in[0];
    const int*   ei     = (const int*)d_in[1];
    const float* ea     = (const float*)d_in[2];
    const float* emb_W  = (const float*)d_in[3];
    const float* emb_b  = (const float*)d_in[4];
    const float* g1_Wl  = (const float*)d_in[5];
    const float* g1_bl  = (const float*)d_in[6];
    const float* g1_Wr  = (const float*)d_in[7];
    const float* g1_br  = (const float*)d_in[8];
    const float* g1_We  = (const float*)d_in[9];
    const float* g1_att = (const float*)d_in[10];
    const float* g1_bias= (const float*)d_in[11];
    const float* g2_Wl  = (const float*)d_in[12];
    const float* g2_bl  = (const float*)d_in[13];
    const float* g2_Wr  = (const float*)d_in[14];
    const float* g2_br  = (const float*)d_in[15];
    const float* g2_We  = (const float*)d_in[16];
    const float* g2_att = (const float*)d_in[17];
    const float* g2_bias= (const float*)d_in[18];
    const float* int_W  = (const float*)d_in[19];
    const float* int_b  = (const float*)d_in[20];
    const float* imp_W  = (const float*)d_in[21];
    const float* imp_b  = (const float*)d_in[22];

    char* ws = (char*)d_ws;
    float* eapart  = (float*)(ws + OFF_EAPART);
    float* eamean  = (float*)(ws + OFF_EAMEAN);
    float* eploop  = (float*)(ws + OFF_EPLOOP);
    int*   counts  = (int*)  (ws + OFF_COUNTS);
    int*   offs    = (int*)  (ws + OFF_OFFS);
    int*   cursor  = (int*)  (ws + OFF_CURSOR);
    int*   csrsrc  = (int*)  (ws + OFF_CSRSRC);
    int*   csreid  = (int*)  (ws + OFF_CSREID);
    float* h_a     = (float*)(ws + OFF_HA);
    float* h_b     = (float*)(ws + OFF_HB);
    float* xl      = (float*)(ws + OFF_XL);
    float* xr      = (float*)(ws + OFF_XR);
    float* outp    = (float*)d_out;

    // edge_attr mean
    ea_colsum_part<<<1024, 256, 0, stream>>>(ea, eapart);
    ea_colsum_final<<<1, 256, 0, stream>>>(eapart, eamean);

    // CSR by destination (self-loops included)
    init_counts<<<(kN + 255) / 256, 256, 0, stream>>>(counts);
    count_edges<<<(kE + 255) / 256, 256, 0, stream>>>(ei, counts);
    scan_kernel<<<1, 1024, 0, stream>>>(counts, offs, cursor);
    scatter_kernel<<<(kE + kN + 255) / 256, 256, 0, stream>>>(ei, cursor, csrsrc, csreid);

    // node embedding
    gemm_bias<128, 64, 32><<<(kN + 31) / 32, 256, 0, stream>>>(x, emb_W, emb_b, h_a, kN);

    // ---- GAT layer 1 ----
    gemm_bias<64, 256, 32><<<(kN + 31) / 32, 256, 0, stream>>>(h_a, g1_Wl, g1_bl, xl, kN);
    gemm_bias<64, 256, 32><<<(kN + 31) / 32, 256, 0, stream>>>(h_a, g1_Wr, g1_br, xr, kN);
    ep_loop_kernel<<<1, 256, 0, stream>>>(eamean, g1_We, eploop);
    gat_node_kernel<<<4096, 256, 0, stream>>>(xl, xr, ea, g1_We, g1_att, eploop, g1_bias,
                                              offs, csrsrc, csreid, h_b);

    // ---- GAT layer 2 ----
    gemm_bias<64, 256, 32><<<(kN + 31) / 32, 256, 0, stream>>>(h_b, g2_Wl, g2_bl, xl, kN);
    gemm_bias<64, 256, 32><<<(kN + 31) / 32, 256, 0, stream>>>(h_b, g2_Wr, g2_br, xr, kN);
    ep_loop_kernel<<<1, 256, 0, stream>>>(eamean, g2_We, eploop);
    gat_node_kernel<<<4096, 256, 0, stream>>>(xl, xr, ea, g2_We, g2_att, eploop, g2_bias,
                                              offs, csrsrc, csreid, h_a);

    // ---- edge heads ----
    edge_head<<<kE / 16, 256, 0, stream>>>(h_a, ei, ea, int_W, int_b, imp_W, imp_b, outp);
}

// Round 3
// 915.692 us; speedup vs baseline: 1.1972x; 1.0483x over previous
//
#include <hip/hip_runtime.h>
#include <math.h>

// Problem constants
constexpr int kN = 25000;
constexpr int kE = 400000;
constexpr int kNodeIn = 128;
constexpr int kEdgeIn = 32;
constexpr int kHid = 64;
constexpr int kHeads = 4;
constexpr int kHC = 256;        // HEADS*HID
constexpr int kIntents = 12;

// ---------------- workspace layout (all 256B aligned) ----------------
constexpr size_t OFF_EAPART = 0;                       // 1024*32 f32 = 131072
constexpr size_t OFF_EAMEAN = 131072;                  // 32 f32 (pad 256)
constexpr size_t OFF_COUNTS = 132352;                  // N i32 -> 100096
constexpr size_t OFF_OFFS   = 232448;                  // N+1 i32 -> 100096
constexpr size_t OFF_CURSOR = 332544;                  // N i32 -> 100096
constexpr size_t OFF_CSRSRC = 432640;                  // (E+N) i32 -> 1700096
constexpr size_t OFF_CSREID = 2132736;                 // (E+N) i32 -> 1700096
constexpr size_t OFF_HA     = 3832832;                 // N*64 f32 = 6400000
constexpr size_t OFF_HB     = 10232832;                // N*64 f32
constexpr size_t OFF_XL     = 16632832;                // N*256 f32 = 25600000
constexpr size_t OFF_XR     = 42232832;                // N*256 f32
// total ~67.8 MB

// ---------------- edge_attr column mean ----------------
__global__ __launch_bounds__(256) void ea_colsum_part(const float* __restrict__ ea,
                                                      float* __restrict__ part)
{
    __shared__ float lds[256];
    const int tid = threadIdx.x;
    const int k = tid & 31, g = tid >> 5;
    float acc = 0.f;
    for (int r = blockIdx.x * 8 + g; r < kE; r += gridDim.x * 8)
        acc += ea[(size_t)r * 32 + k];
    lds[tid] = acc; __syncthreads();
    if (tid < 128) lds[tid] += lds[tid + 128]; __syncthreads();
    if (tid < 64)  lds[tid] += lds[tid + 64];  __syncthreads();
    if (tid < 32)  part[blockIdx.x * 32 + k] = lds[tid] + lds[tid + 32];
}

__global__ __launch_bounds__(256) void ea_colsum_final(const float* __restrict__ part,
                                                       float* __restrict__ ea_mean)
{
    __shared__ float lds[256];
    const int tid = threadIdx.x;
    const int k = tid & 31, g = tid >> 5;
    float acc = 0.f;
    for (int p = g; p < 1024; p += 8) acc += part[p * 32 + k];
    lds[tid] = acc; __syncthreads();
    if (tid < 128) lds[tid] += lds[tid + 128]; __syncthreads();
    if (tid < 64)  lds[tid] += lds[tid + 64];  __syncthreads();
    if (tid < 32)  ea_mean[k] = (lds[tid] + lds[tid + 32]) * (1.0f / (float)kE);
}

// ---------------- CSR build ----------------
__global__ __launch_bounds__(256) void init_counts(int* __restrict__ counts)
{
    int i = blockIdx.x * 256 + threadIdx.x;
    if (i < kN) counts[i] = 1;   // self-loop pre-counted
}

__global__ __launch_bounds__(256) void count_edges(const int* __restrict__ ei,
                                                   int* __restrict__ counts)
{
    int e = blockIdx.x * 256 + threadIdx.x;
    if (e < kE) atomicAdd(&counts[ei[kE + e]], 1);
}

__global__ __launch_bounds__(1024) void scan_kernel(const int* __restrict__ counts,
                                                    int* __restrict__ offsets,
                                                    int* __restrict__ cursor)
{
    __shared__ int lds[1024];
    const int tid = threadIdx.x;
    const int base = tid * 25;
    int local = 0;
#pragma unroll 5
    for (int i = 0; i < 25; i++) {
        int idx = base + i;
        if (idx < kN) local += counts[idx];
    }
    lds[tid] = local; __syncthreads();
    for (int d = 1; d < 1024; d <<= 1) {
        int t = (tid >= d) ? lds[tid - d] : 0;
        __syncthreads();
        lds[tid] += t;
        __syncthreads();
    }
    int run = lds[tid] - local;   // exclusive prefix
    for (int i = 0; i < 25; i++) {
        int idx = base + i;
        if (idx < kN) {
            offsets[idx] = run;
            cursor[idx]  = run;
            run += counts[idx];
        }
    }
    if (tid == 1023) offsets[kN] = lds[1023];
}

__global__ __launch_bounds__(256) void scatter_kernel(const int* __restrict__ ei,
                                                      int* __restrict__ cursor,
                                                      int* __restrict__ csr_src,
                                                      int* __restrict__ csr_eid)
{
    int gid = blockIdx.x * 256 + threadIdx.x;
    if (gid < kE) {
        int s = ei[gid];
        int d = ei[kE + gid];
        int p = atomicAdd(&cursor[d], 1);
        csr_src[p] = s;
        csr_eid[p] = gid;
    } else if (gid < kE + kN) {
        int n = gid - kE;
        int p = atomicAdd(&cursor[n], 1);
        csr_src[p] = n;
        csr_eid[p] = kE;   // sentinel: self-loop
    }
}

// ---------------- small dense GEMM: out[M,KO] = A[M,KI]@W[KI,KO] + b ----------------
template<int KI, int KO, int RPB>
__global__ __launch_bounds__(256) void gemm_bias(const float* __restrict__ A,
                                                 const float* __restrict__ W,
                                                 const float* __restrict__ bias,
                                                 float* __restrict__ out, int M)
{
    constexpr int CG  = 256 / KO;   // column groups
    constexpr int RPT = RPB / CG;   // rows per thread
    __shared__ __align__(16) float a_lds[RPB * KI];
    const int tid = threadIdx.x;
    const int col = tid % KO;
    const int g   = tid / KO;
    const int row0 = blockIdx.x * RPB;

    // stage A tile (rows are contiguous)
    const float4* Ab = (const float4*)(A + (size_t)row0 * KI);
    float4* L4 = (float4*)a_lds;
    constexpr int ELEM4 = RPB * KI / 4;
    for (int i = tid; i < ELEM4; i += 256) {
        int r = (i * 4) / KI;
        float4 v = make_float4(0.f, 0.f, 0.f, 0.f);
        if (row0 + r < M) v = Ab[i];
        L4[i] = v;
    }
    __syncthreads();

    float acc[RPT];
#pragma unroll
    for (int r = 0; r < RPT; r++) acc[r] = 0.f;
    const float* arow = a_lds + (size_t)(g * RPT) * KI;
    for (int k0 = 0; k0 < KI; k0 += 4) {
        float w0 = W[(k0 + 0) * KO + col];
        float w1 = W[(k0 + 1) * KO + col];
        float w2 = W[(k0 + 2) * KO + col];
        float w3 = W[(k0 + 3) * KO + col];
#pragma unroll
        for (int r = 0; r < RPT; r++) {
            const float4 a = *(const float4*)(arow + r * KI + k0);
            acc[r] += a.x * w0 + a.y * w1 + a.z * w2 + a.w * w3;
        }
    }
    const float bv = bias[col];
#pragma unroll
    for (int r = 0; r < RPT; r++) {
        int row = row0 + g * RPT + r;
        if (row < M) out[(size_t)row * KO + col] = acc[r] + bv;
    }
}

// ---------------- fused GATv2 layer ----------------
// block = 256 threads; wave w = head w, lane = channel.
// R2: unshifted exp (softmax is shift-invariant; |logit| ~ O(10) << 88, so
// exp never overflows) -> no serial online-softmax chain; 8-edge batches with
// independent accumulators; self-loops resolved at staging (ea_mean row);
// 64-edge staging rounds with 2 barriers; 32-bit gather offsets.
__global__ __launch_bounds__(256) void gat_node_kernel(
    const float* __restrict__ xl, const float* __restrict__ xr,
    const float* __restrict__ ea, const float* __restrict__ eamean,
    const float* __restrict__ We, const float* __restrict__ att,
    const float* __restrict__ gbias,
    const int* __restrict__ offsets, const int* __restrict__ csr_src,
    const int* __restrict__ csr_eid, float* __restrict__ h_out)
{
    constexpr int ROWP = 36;                      // padded ea row (floats)
    __shared__ __align__(16) float ea_lds[64 * ROWP];
    __shared__ __align__(16) int s_src[64];
    __shared__ float red[256];
    const int tid = threadIdx.x;

    // per-thread column of We (32 regs) + att
    float we[32];
#pragma unroll
    for (int kk = 0; kk < 32; kk++) we[kk] = We[kk * 256 + tid];
    const float att_r = att[tid];

    for (int n = blockIdx.x; n < kN; n += gridDim.x) {
        const int o0 = offsets[n], o1 = offsets[n + 1];
        const float xr_r = xr[n * 256 + tid];
        float den = 0.f, acc = 0.f;

        for (int b0 = o0; b0 < o1; b0 += 64) {
            const int cnt = min(64, o1 - b0);
            __syncthreads();
            if (tid < cnt) s_src[tid] = csr_src[b0 + tid];
            {   // stage edge_attr rows (ea_mean for self-loop sentinels): 4 threads/edge
                const int j = tid >> 2, q0 = (tid & 3) * 2;
                if (j < cnt) {
                    const int eid = csr_eid[b0 + j];
                    const float4* srcp = (eid < kE) ? (const float4*)(ea + (size_t)eid * 32)
                                                    : (const float4*)eamean;
                    float4* dst = (float4*)(ea_lds + j * ROWP);
                    dst[q0]     = srcp[q0];
                    dst[q0 + 1] = srcp[q0 + 1];
                }
            }
            __syncthreads();

            const int full = cnt & ~7;
            int i = 0;
            for (; i < full; i += 8) {
                const int4 ss0 = *(const int4*)&s_src[i];
                const int4 ss1 = *(const int4*)&s_src[i + 4];
                const int sv[8] = {ss0.x, ss0.y, ss0.z, ss0.w,
                                   ss1.x, ss1.y, ss1.z, ss1.w};
                float xls[8], c[8];
#pragma unroll
                for (int u = 0; u < 8; u++)
                    xls[u] = xl[sv[u] * 256 + tid];       // 8 gathers in flight
#pragma unroll
                for (int u = 0; u < 8; u++) {
                    const float4* av = (const float4*)(ea_lds + (i + u) * ROWP);
                    float ep = 0.f;
#pragma unroll
                    for (int q = 0; q < 8; q++) {
                        const float4 a = av[q];
                        ep += a.x * we[4 * q + 0];
                        ep += a.y * we[4 * q + 1];
                        ep += a.z * we[4 * q + 2];
                        ep += a.w * we[4 * q + 3];
                    }
                    float v = xls[u] + xr_r + ep;
                    v = fmaxf(v, 0.f) + 0.2f * fminf(v, 0.f);   // leaky_relu 0.2
                    c[u] = att_r * v;
                }
                // 8 interleaved butterfly chains
#pragma unroll
                for (int d = 1; d < 64; d <<= 1) {
#pragma unroll
                    for (int u = 0; u < 8; u++) c[u] += __shfl_xor(c[u], d);
                }
#pragma unroll
                for (int u = 0; u < 8; u++) {
                    const float pe = __expf(c[u]);        // unshifted: no chain
                    den += pe;
                    acc += pe * xls[u];
                }
            }
            for (; i < cnt; i++) {                        // tail, unmasked
                const int s = s_src[i];
                const float xls = xl[s * 256 + tid];
                const float4* av = (const float4*)(ea_lds + i * ROWP);
                float ep = 0.f;
#pragma unroll
                for (int q = 0; q < 8; q++) {
                    const float4 a = av[q];
                    ep += a.x * we[4 * q + 0];
                    ep += a.y * we[4 * q + 1];
                    ep += a.z * we[4 * q + 2];
                    ep += a.w * we[4 * q + 3];
                }
                float v = xls + xr_r + ep;
                v = fmaxf(v, 0.f) + 0.2f * fminf(v, 0.f);
                float cc = att_r * v;
#pragma unroll
                for (int d = 1; d < 64; d <<= 1) cc += __shfl_xor(cc, d);
                const float pe = __expf(cc);
                den += pe;
                acc += pe * xls;
            }
        }
        __syncthreads();
        red[tid] = acc / den;
        __syncthreads();
        if (tid < 64) {
            float sres = red[tid] + red[tid + 64] + red[tid + 128] + red[tid + 192];
            h_out[n * 64 + tid] = fmaxf(0.25f * sres + gbias[tid], 0.f);
        }
    }
}

// ---------------- final edge heads: intent logits + importance ----------------
__global__ __launch_bounds__(256) void edge_head(
    const float* __restrict__ h, const int* __restrict__ ei,
    const float* __restrict__ ea, const float* __restrict__ intW,
    const float* __restrict__ intb, const float* __restrict__ impW,
    const float* __restrict__ impb, float* __restrict__ out)
{
    __shared__ __align__(16) float rep[16 * 164];
    __shared__ __align__(16) float W13[13 * 164];
    __shared__ int s_src[16], s_dst[16];
    const int tid = threadIdx.x;
    const int e0 = blockIdx.x * 16;

    for (int i = tid; i < 13 * 160; i += 256) {
        int k = i / 13, c = i % 13;
        W13[c * 164 + k] = (c < 12) ? intW[k * 12 + c] : impW[k];
    }
    if (tid < 16) {
        s_src[tid] = ei[e0 + tid];
        s_dst[tid] = ei[kE + e0 + tid];
    }
    __syncthreads();

    for (int i = tid; i < 16 * 160; i += 256) {
        int j = i / 160, k = i % 160;
        float v;
        if (k < 64)       v = h[(size_t)s_src[j] * 64 + k];
        else if (k < 128) v = h[(size_t)s_dst[j] * 64 + (k - 64)];
        else              v = ea[(size_t)(e0 + j) * 32 + (k - 128)];
        rep[j * 164 + k] = fmaxf(v, 0.f);   // relu(concat)
    }
    __syncthreads();

    if (tid < 16 * 13) {
        int j = tid / 13, c = tid % 13;
        const float4* rp = (const float4*)(rep + j * 164);
        const float4* wp = (const float4*)(W13 + c * 164);
        float acc = 0.f;
#pragma unroll 8
        for (int q = 0; q < 40; q++) {
            float4 a = rp[q], w = wp[q];
            acc += a.x * w.x + a.y * w.y + a.z * w.z + a.w * w.w;
        }
        int eg = e0 + j;
        if (c < 12) {
            out[(size_t)eg * 12 + c] = acc + intb[c];
        } else {
            float z = acc + impb[0];
            out[(size_t)kE * 12 + eg] = 1.f / (1.f + __expf(-z));
        }
    }
}

// ---------------- launch ----------------
extern "C" void kernel_launch(void* const* d_in, const int* in_sizes, int n_in,
                              void* d_out, int out_size, void* d_ws, size_t ws_size,
                              hipStream_t stream)
{
    (void)in_sizes; (void)n_in; (void)out_size; (void)ws_size;

    const float* x      = (const float*)d_in[0];
    const int*   ei     = (const int*)d_in[1];
    const float* ea     = (const float*)d_in[2];
    const float* emb_W  = (const float*)d_in[3];
    const float* emb_b  = (const float*)d_in[4];
    const float* g1_Wl  = (const float*)d_in[5];
    const float* g1_bl  = (const float*)d_in[6];
    const float* g1_Wr  = (const float*)d_in[7];
    const float* g1_br  = (const float*)d_in[8];
    const float* g1_We  = (const float*)d_in[9];
    const float* g1_att = (const float*)d_in[10];
    const float* g1_bias= (const float*)d_in[11];
    const float* g2_Wl  = (const float*)d_in[12];
    const float* g2_bl  = (const float*)d_in[13];
    const float* g2_Wr  = (const float*)d_in[14];
    const float* g2_br  = (const float*)d_in[15];
    const float* g2_We  = (const float*)d_in[16];
    const float* g2_att = (const float*)d_in[17];
    const float* g2_bias= (const float*)d_in[18];
    const float* int_W  = (const float*)d_in[19];
    const float* int_b  = (const float*)d_in[20];
    const float* imp_W  = (const float*)d_in[21];
    const float* imp_b  = (const float*)d_in[22];

    char* ws = (char*)d_ws;
    float* eapart  = (float*)(ws + OFF_EAPART);
    float* eamean  = (float*)(ws + OFF_EAMEAN);
    int*   counts  = (int*)  (ws + OFF_COUNTS);
    int*   offs    = (int*)  (ws + OFF_OFFS);
    int*   cursor  = (int*)  (ws + OFF_CURSOR);
    int*   csrsrc  = (int*)  (ws + OFF_CSRSRC);
    int*   csreid  = (int*)  (ws + OFF_CSREID);
    float* h_a     = (float*)(ws + OFF_HA);
    float* h_b     = (float*)(ws + OFF_HB);
    float* xl      = (float*)(ws + OFF_XL);
    float* xr      = (float*)(ws + OFF_XR);
    float* outp    = (float*)d_out;

    // edge_attr mean
    ea_colsum_part<<<1024, 256, 0, stream>>>(ea, eapart);
    ea_colsum_final<<<1, 256, 0, stream>>>(eapart, eamean);

    // CSR by destination (self-loops included)
    init_counts<<<(kN + 255) / 256, 256, 0, stream>>>(counts);
    count_edges<<<(kE + 255) / 256, 256, 0, stream>>>(ei, counts);
    scan_kernel<<<1, 1024, 0, stream>>>(counts, offs, cursor);
    scatter_kernel<<<(kE + kN + 255) / 256, 256, 0, stream>>>(ei, cursor, csrsrc, csreid);

    // node embedding
    gemm_bias<128, 64, 32><<<(kN + 31) / 32, 256, 0, stream>>>(x, emb_W, emb_b, h_a, kN);

    // ---- GAT layer 1 ----
    gemm_bias<64, 256, 32><<<(kN + 31) / 32, 256, 0, stream>>>(h_a, g1_Wl, g1_bl, xl, kN);
    gemm_bias<64, 256, 32><<<(kN + 31) / 32, 256, 0, stream>>>(h_a, g1_Wr, g1_br, xr, kN);
    gat_node_kernel<<<4096, 256, 0, stream>>>(xl, xr, ea, eamean, g1_We, g1_att, g1_bias,
                                              offs, csrsrc, csreid, h_b);

    // ---- GAT layer 2 ----
    gemm_bias<64, 256, 32><<<(kN + 31) / 32, 256, 0, stream>>>(h_b, g2_Wl, g2_bl, xl, kN);
    gemm_bias<64, 256, 32><<<(kN + 31) / 32, 256, 0, stream>>>(h_b, g2_Wr, g2_br, xr, kN);
    gat_node_kernel<<<4096, 256, 0, stream>>>(xl, xr, ea, eamean, g2_We, g2_att, g2_bias,
                                              offs, csrsrc, csreid, h_a);

    // ---- edge heads ----
    edge_head<<<kE / 16, 256, 0, stream>>>(h_a, ei, ea, int_W, int_b, imp_W, imp_b, outp);
}

// Round 4
// 837.322 us; speedup vs baseline: 1.3092x; 1.0936x over previous
//
#include <hip/hip_runtime.h>
#include <math.h>

// Problem constants
constexpr int kN = 25000;
constexpr int kE = 400000;
constexpr int kNodeIn = 128;
constexpr int kEdgeIn = 32;
constexpr int kHid = 64;
constexpr int kHeads = 4;
constexpr int kHC = 256;        // HEADS*HID
constexpr int kIntents = 12;

typedef __attribute__((ext_vector_type(8))) short bf16x8s;   // 8 bf16 (4 VGPRs)
typedef __attribute__((ext_vector_type(4))) float f32x4;

__device__ __forceinline__ unsigned short f2bf(float f) {
    unsigned u = __builtin_bit_cast(unsigned, f);
    unsigned r = (u + 0x7FFFu + ((u >> 16) & 1u)) >> 16;     // RNE
    return (unsigned short)r;
}
__device__ __forceinline__ float bf2f(unsigned short h) {
    unsigned u = ((unsigned)h) << 16;
    return __builtin_bit_cast(float, u);
}

// ---------------- workspace layout (all 256B aligned) ----------------
constexpr size_t OFF_EAPART = 0;                       // 1024*32 f32 = 131072
constexpr size_t OFF_EAMEAN = 131072;                  // 32 f32 (pad 256)
constexpr size_t OFF_COUNTS = 132352;                  // N i32 -> 100096
constexpr size_t OFF_OFFS   = 232448;                  // N+1 i32 -> 100096
constexpr size_t OFF_CURSOR = 332544;                  // N i32 -> 100096
constexpr size_t OFF_CSRSRC = 432640;                  // (E+N) i32 -> 1700096
constexpr size_t OFF_CSREID = 2132736;                 // (E+N) i32 -> 1700096
constexpr size_t OFF_HA     = 3832832;                 // N*64 f32 = 6400000
constexpr size_t OFF_HB     = 10232832;                // N*64 f32
constexpr size_t OFF_XL     = 16632832;                // N*256 f32 = 25600000
constexpr size_t OFF_XR     = 42232832;                // N*256 f32
constexpr size_t OFF_WE1H   = 67832832;                // 32*256 u16 = 16384
constexpr size_t OFF_WE1L   = 67849216;
constexpr size_t OFF_WE2H   = 67865600;
constexpr size_t OFF_WE2L   = 67881984;                // end ~67.9 MB

// ---------------- edge_attr column mean ----------------
__global__ __launch_bounds__(256) void ea_colsum_part(const float* __restrict__ ea,
                                                      float* __restrict__ part)
{
    __shared__ float lds[256];
    const int tid = threadIdx.x;
    const int k = tid & 31, g = tid >> 5;
    float acc = 0.f;
    for (int r = blockIdx.x * 8 + g; r < kE; r += gridDim.x * 8)
        acc += ea[(size_t)r * 32 + k];
    lds[tid] = acc; __syncthreads();
    if (tid < 128) lds[tid] += lds[tid + 128]; __syncthreads();
    if (tid < 64)  lds[tid] += lds[tid + 64];  __syncthreads();
    if (tid < 32)  part[blockIdx.x * 32 + k] = lds[tid] + lds[tid + 32];
}

__global__ __launch_bounds__(256) void ea_colsum_final(const float* __restrict__ part,
                                                       float* __restrict__ ea_mean)
{
    __shared__ float lds[256];
    const int tid = threadIdx.x;
    const int k = tid & 31, g = tid >> 5;
    float acc = 0.f;
    for (int p = g; p < 1024; p += 8) acc += part[p * 32 + k];
    lds[tid] = acc; __syncthreads();
    if (tid < 128) lds[tid] += lds[tid + 128]; __syncthreads();
    if (tid < 64)  lds[tid] += lds[tid + 64];  __syncthreads();
    if (tid < 32)  ea_mean[k] = (lds[tid] + lds[tid + 32]) * (1.0f / (float)kE);
}

// ---------------- We -> bf16 hi/lo split (both layers) ----------------
__global__ __launch_bounds__(256) void we_split(const float* __restrict__ W1,
                                                const float* __restrict__ W2,
                                                unsigned short* __restrict__ h1,
                                                unsigned short* __restrict__ l1,
                                                unsigned short* __restrict__ h2,
                                                unsigned short* __restrict__ l2)
{
    const int b = blockIdx.x, tid = threadIdx.x;
    const int k = b & 31;
    const float* W = (b < 32) ? W1 : W2;
    unsigned short* H = (b < 32) ? h1 : h2;
    unsigned short* L = (b < 32) ? l1 : l2;
    const float f = W[k * 256 + tid];
    const unsigned short hb = f2bf(f);
    H[k * 256 + tid] = hb;
    L[k * 256 + tid] = f2bf(f - bf2f(hb));
}

// ---------------- CSR build ----------------
__global__ __launch_bounds__(256) void init_counts(int* __restrict__ counts)
{
    int i = blockIdx.x * 256 + threadIdx.x;
    if (i < kN) counts[i] = 1;   // self-loop pre-counted
}

__global__ __launch_bounds__(256) void count_edges(const int* __restrict__ ei,
                                                   int* __restrict__ counts)
{
    int e = blockIdx.x * 256 + threadIdx.x;
    if (e < kE) atomicAdd(&counts[ei[kE + e]], 1);
}

__global__ __launch_bounds__(1024) void scan_kernel(const int* __restrict__ counts,
                                                    int* __restrict__ offsets,
                                                    int* __restrict__ cursor)
{
    __shared__ int lds[1024];
    const int tid = threadIdx.x;
    const int base = tid * 25;
    int local = 0;
#pragma unroll 5
    for (int i = 0; i < 25; i++) {
        int idx = base + i;
        if (idx < kN) local += counts[idx];
    }
    lds[tid] = local; __syncthreads();
    for (int d = 1; d < 1024; d <<= 1) {
        int t = (tid >= d) ? lds[tid - d] : 0;
        __syncthreads();
        lds[tid] += t;
        __syncthreads();
    }
    int run = lds[tid] - local;   // exclusive prefix
    for (int i = 0; i < 25; i++) {
        int idx = base + i;
        if (idx < kN) {
            offsets[idx] = run;
            cursor[idx]  = run;
            run += counts[idx];
        }
    }
    if (tid == 1023) offsets[kN] = lds[1023];
}

__global__ __launch_bounds__(256) void scatter_kernel(const int* __restrict__ ei,
                                                      int* __restrict__ cursor,
                                                      int* __restrict__ csr_src,
                                                      int* __restrict__ csr_eid)
{
    int gid = blockIdx.x * 256 + threadIdx.x;
    if (gid < kE) {
        int s = ei[gid];
        int d = ei[kE + gid];
        int p = atomicAdd(&cursor[d], 1);
        csr_src[p] = s;
        csr_eid[p] = gid;
    } else if (gid < kE + kN) {
        int n = gid - kE;
        int p = atomicAdd(&cursor[n], 1);
        csr_src[p] = n;
        csr_eid[p] = kE;   // sentinel: self-loop
    }
}

// ---------------- small dense GEMM: out[M,KO] = A[M,KI]@W[KI,KO] + b ----------------
template<int KI, int KO, int RPB>
__global__ __launch_bounds__(256) void gemm_bias(const float* __restrict__ A,
                                                 const float* __restrict__ W,
                                                 const float* __restrict__ bias,
                                                 float* __restrict__ out, int M)
{
    constexpr int CG  = 256 / KO;   // column groups
    constexpr int RPT = RPB / CG;   // rows per thread
    __shared__ __align__(16) float a_lds[RPB * KI];
    const int tid = threadIdx.x;
    const int col = tid % KO;
    const int g   = tid / KO;
    const int row0 = blockIdx.x * RPB;

    // stage A tile (rows are contiguous)
    const float4* Ab = (const float4*)(A + (size_t)row0 * KI);
    float4* L4 = (float4*)a_lds;
    constexpr int ELEM4 = RPB * KI / 4;
    for (int i = tid; i < ELEM4; i += 256) {
        int r = (i * 4) / KI;
        float4 v = make_float4(0.f, 0.f, 0.f, 0.f);
        if (row0 + r < M) v = Ab[i];
        L4[i] = v;
    }
    __syncthreads();

    float acc[RPT];
#pragma unroll
    for (int r = 0; r < RPT; r++) acc[r] = 0.f;
    const float* arow = a_lds + (size_t)(g * RPT) * KI;
    for (int k0 = 0; k0 < KI; k0 += 4) {
        float w0 = W[(k0 + 0) * KO + col];
        float w1 = W[(k0 + 1) * KO + col];
        float w2 = W[(k0 + 2) * KO + col];
        float w3 = W[(k0 + 3) * KO + col];
#pragma unroll
        for (int r = 0; r < RPT; r++) {
            const float4 a = *(const float4*)(arow + r * KI + k0);
            acc[r] += a.x * w0 + a.y * w1 + a.z * w2 + a.w * w3;
        }
    }
    const float bv = bias[col];
#pragma unroll
    for (int r = 0; r < RPT; r++) {
        int row = row0 + g * RPT + r;
        if (row < M) out[(size_t)row * KO + col] = acc[r] + bv;
    }
}

// ---------------- fused GATv2 layer ----------------
// block = 256 threads; wave w = head w, lane = channel.
// R3: ep = ea@We moved to MFMA (split-bf16 x3 products, fp32-faithful) over
// 32-edge tiles; inner loop reads ep from LDS instead of 32 VALU FMAs/edge.
__global__ __launch_bounds__(256) void gat_node_kernel(
    const float* __restrict__ xl, const float* __restrict__ xr,
    const float* __restrict__ ea, const float* __restrict__ eamean,
    const unsigned short* __restrict__ weh, const unsigned short* __restrict__ wel,
    const float* __restrict__ att, const float* __restrict__ gbias,
    const int* __restrict__ offsets, const int* __restrict__ csr_src,
    const int* __restrict__ csr_eid, float* __restrict__ h_out)
{
    constexpr int ROWS = 40;                       // padded ea row (shorts), 80B: 16B-aligned frags
    constexpr int EPP  = 257;                      // padded ep row (floats)
    __shared__ __align__(16) unsigned short ea_hi[32 * ROWS];
    __shared__ __align__(16) unsigned short ea_lo[32 * ROWS];
    __shared__ __align__(16) float ep_lds[32 * EPP];
    __shared__ __align__(16) int s_src[32];
    __shared__ float red[256];
    const int tid  = threadIdx.x;
    const int w    = tid >> 6;
    const int lane = tid & 63;

    // B fragments (We hi/lo) for this wave's 4 N-tiles of 16 channels.
    // mfma_f32_16x16x32_bf16 B layout: col = lane&15, k = (lane>>4)*8 + j
    bf16x8s bh[4], bl[4];
#pragma unroll
    for (int nt = 0; nt < 4; nt++) {
        const int c = w * 64 + nt * 16 + (lane & 15);
        const int k0 = (lane >> 4) * 8;
#pragma unroll
        for (int j = 0; j < 8; j++) {
            bh[nt][j] = (short)weh[(k0 + j) * 256 + c];
            bl[nt][j] = (short)wel[(k0 + j) * 256 + c];
        }
    }
    const float att_r = att[tid];
    // A-frag LDS offsets (shorts): row = lane&15 (edge in tile), k-group = lane>>4
    const int aoff = (lane & 15) * ROWS + (lane >> 4) * 8;

    for (int n = blockIdx.x; n < kN; n += gridDim.x) {
        const int o0 = offsets[n], o1 = offsets[n + 1];
        const float xr_r = xr[n * 256 + tid];
        float den = 0.f, acc = 0.f;

        for (int b0 = o0; b0 < o1; b0 += 32) {
            const int cnt = min(32, o1 - b0);
            __syncthreads();
            if (tid < cnt) s_src[tid] = csr_src[b0 + tid];
            {   // stage ea rows as bf16 hi/lo: 8 threads per edge, 1 float4 each
                const int j = tid >> 3, q = tid & 7;
                if (j < cnt) {
                    const int eid = csr_eid[b0 + j];
                    const float4* srcp = (eid < kE) ? (const float4*)(ea + (size_t)eid * 32)
                                                    : (const float4*)eamean;
                    const float4 f = srcp[q];
                    const unsigned short h0 = f2bf(f.x), h1 = f2bf(f.y),
                                         h2 = f2bf(f.z), h3 = f2bf(f.w);
                    const unsigned short g0 = f2bf(f.x - bf2f(h0)), g1 = f2bf(f.y - bf2f(h1)),
                                         g2 = f2bf(f.z - bf2f(h2)), g3 = f2bf(f.w - bf2f(h3));
                    const unsigned long long ph =
                        (unsigned long long)h0 | ((unsigned long long)h1 << 16) |
                        ((unsigned long long)h2 << 32) | ((unsigned long long)h3 << 48);
                    const unsigned long long pl =
                        (unsigned long long)g0 | ((unsigned long long)g1 << 16) |
                        ((unsigned long long)g2 << 32) | ((unsigned long long)g3 << 48);
                    *(unsigned long long*)&ea_hi[j * ROWS + q * 4] = ph;
                    *(unsigned long long*)&ea_lo[j * ROWS + q * 4] = pl;
                }
            }
            __syncthreads();

            // ---- MFMA: ep[32][256] = ea @ We (3-product split-bf16) ----
            {
                const bf16x8s ah0 = *(const bf16x8s*)&ea_hi[aoff];
                const bf16x8s ah1 = *(const bf16x8s*)&ea_hi[16 * ROWS + aoff];
                const bf16x8s al0 = *(const bf16x8s*)&ea_lo[aoff];
                const bf16x8s al1 = *(const bf16x8s*)&ea_lo[16 * ROWS + aoff];
                const int cbase = w * 64 + (lane & 15);
                const int rbase = (lane >> 4) * 4;
#pragma unroll
                for (int nt = 0; nt < 4; nt++) {
                    f32x4 a0 = {0.f, 0.f, 0.f, 0.f};
                    a0 = __builtin_amdgcn_mfma_f32_16x16x32_bf16(ah0, bh[nt], a0, 0, 0, 0);
                    a0 = __builtin_amdgcn_mfma_f32_16x16x32_bf16(ah0, bl[nt], a0, 0, 0, 0);
                    a0 = __builtin_amdgcn_mfma_f32_16x16x32_bf16(al0, bh[nt], a0, 0, 0, 0);
                    f32x4 a1 = {0.f, 0.f, 0.f, 0.f};
                    a1 = __builtin_amdgcn_mfma_f32_16x16x32_bf16(ah1, bh[nt], a1, 0, 0, 0);
                    a1 = __builtin_amdgcn_mfma_f32_16x16x32_bf16(ah1, bl[nt], a1, 0, 0, 0);
                    a1 = __builtin_amdgcn_mfma_f32_16x16x32_bf16(al1, bh[nt], a1, 0, 0, 0);
                    const int cc = cbase + nt * 16;
#pragma unroll
                    for (int r = 0; r < 4; r++) {
                        ep_lds[(rbase + r) * EPP + cc]        = a0[r];
                        ep_lds[(16 + rbase + r) * EPP + cc]   = a1[r];
                    }
                }
            }
            __syncthreads();

            const int full = cnt & ~7;
            int i = 0;
            for (; i < full; i += 8) {
                const int4 ss0 = *(const int4*)&s_src[i];
                const int4 ss1 = *(const int4*)&s_src[i + 4];
                const int sv[8] = {ss0.x, ss0.y, ss0.z, ss0.w,
                                   ss1.x, ss1.y, ss1.z, ss1.w};
                float xls[8], c[8];
#pragma unroll
                for (int u = 0; u < 8; u++)
                    xls[u] = xl[sv[u] * 256 + tid];       // 8 gathers in flight
#pragma unroll
                for (int u = 0; u < 8; u++) {
                    float v = xls[u] + xr_r + ep_lds[(i + u) * EPP + tid];
                    v = fmaxf(v, 0.f) + 0.2f * fminf(v, 0.f);   // leaky_relu 0.2
                    c[u] = att_r * v;
                }
                // 8 interleaved butterfly chains
#pragma unroll
                for (int d = 1; d < 64; d <<= 1) {
#pragma unroll
                    for (int u = 0; u < 8; u++) c[u] += __shfl_xor(c[u], d);
                }
#pragma unroll
                for (int u = 0; u < 8; u++) {
                    const float pe = __expf(c[u]);        // unshifted: softmax shift-invariant
                    den += pe;
                    acc += pe * xls[u];
                }
            }
            for (; i < cnt; i++) {                        // tail
                const int s = s_src[i];
                const float xls = xl[s * 256 + tid];
                float v = xls + xr_r + ep_lds[i * EPP + tid];
                v = fmaxf(v, 0.f) + 0.2f * fminf(v, 0.f);
                float cc = att_r * v;
#pragma unroll
                for (int d = 1; d < 64; d <<= 1) cc += __shfl_xor(cc, d);
                const float pe = __expf(cc);
                den += pe;
                acc += pe * xls;
            }
        }
        __syncthreads();
        red[tid] = acc / den;
        __syncthreads();
        if (tid < 64) {
            float sres = red[tid] + red[tid + 64] + red[tid + 128] + red[tid + 192];
            h_out[n * 64 + tid] = fmaxf(0.25f * sres + gbias[tid], 0.f);
        }
    }
}

// ---------------- final edge heads: intent logits + importance ----------------
__global__ __launch_bounds__(256) void edge_head(
    const float* __restrict__ h, const int* __restrict__ ei,
    const float* __restrict__ ea, const float* __restrict__ intW,
    const float* __restrict__ intb, const float* __restrict__ impW,
    const float* __restrict__ impb, float* __restrict__ out)
{
    __shared__ __align__(16) float rep[16 * 164];
    __shared__ __align__(16) float W13[13 * 164];
    __shared__ int s_src[16], s_dst[16];
    const int tid = threadIdx.x;
    const int e0 = blockIdx.x * 16;

    for (int i = tid; i < 13 * 160; i += 256) {
        int k = i / 13, c = i % 13;
        W13[c * 164 + k] = (c < 12) ? intW[k * 12 + c] : impW[k];
    }
    if (tid < 16) {
        s_src[tid] = ei[e0 + tid];
        s_dst[tid] = ei[kE + e0 + tid];
    }
    __syncthreads();

    for (int i = tid; i < 16 * 160; i += 256) {
        int j = i / 160, k = i % 160;
        float v;
        if (k < 64)       v = h[(size_t)s_src[j] * 64 + k];
        else if (k < 128) v = h[(size_t)s_dst[j] * 64 + (k - 64)];
        else              v = ea[(size_t)(e0 + j) * 32 + (k - 128)];
        rep[j * 164 + k] = fmaxf(v, 0.f);   // relu(concat)
    }
    __syncthreads();

    if (tid < 16 * 13) {
        int j = tid / 13, c = tid % 13;
        const float4* rp = (const float4*)(rep + j * 164);
        const float4* wp = (const float4*)(W13 + c * 164);
        float acc = 0.f;
#pragma unroll 8
        for (int q = 0; q < 40; q++) {
            float4 a = rp[q], w = wp[q];
            acc += a.x * w.x + a.y * w.y + a.z * w.z + a.w * w.w;
        }
        int eg = e0 + j;
        if (c < 12) {
            out[(size_t)eg * 12 + c] = acc + intb[c];
        } else {
            float z = acc + impb[0];
            out[(size_t)kE * 12 + eg] = 1.f / (1.f + __expf(-z));
        }
    }
}

// ---------------- launch ----------------
extern "C" void kernel_launch(void* const* d_in, const int* in_sizes, int n_in,
                              void* d_out, int out_size, void* d_ws, size_t ws_size,
                              hipStream_t stream)
{
    (void)in_sizes; (void)n_in; (void)out_size; (void)ws_size;

    const float* x      = (const float*)d_in[0];
    const int*   ei     = (const int*)d_in[1];
    const float* ea     = (const float*)d_in[2];
    const float* emb_W  = (const float*)d_in[3];
    const float* emb_b  = (const float*)d_in[4];
    const float* g1_Wl  = (const float*)d_in[5];
    const float* g1_bl  = (const float*)d_in[6];
    const float* g1_Wr  = (const float*)d_in[7];
    const float* g1_br  = (const float*)d_in[8];
    const float* g1_We  = (const float*)d_in[9];
    const float* g1_att = (const float*)d_in[10];
    const float* g1_bias= (const float*)d_in[11];
    const float* g2_Wl  = (const float*)d_in[12];
    const float* g2_bl  = (const float*)d_in[13];
    const float* g2_Wr  = (const float*)d_in[14];
    const float* g2_br  = (const float*)d_in[15];
    const float* g2_We  = (const float*)d_in[16];
    const float* g2_att = (const float*)d_in[17];
    const float* g2_bias= (const float*)d_in[18];
    const float* int_W  = (const float*)d_in[19];
    const float* int_b  = (const float*)d_in[20];
    const float* imp_W  = (const float*)d_in[21];
    const float* imp_b  = (const float*)d_in[22];

    char* ws = (char*)d_ws;
    float* eapart  = (float*)(ws + OFF_EAPART);
    float* eamean  = (float*)(ws + OFF_EAMEAN);
    int*   counts  = (int*)  (ws + OFF_COUNTS);
    int*   offs    = (int*)  (ws + OFF_OFFS);
    int*   cursor  = (int*)  (ws + OFF_CURSOR);
    int*   csrsrc  = (int*)  (ws + OFF_CSRSRC);
    int*   csreid  = (int*)  (ws + OFF_CSREID);
    float* h_a     = (float*)(ws + OFF_HA);
    float* h_b     = (float*)(ws + OFF_HB);
    float* xl      = (float*)(ws + OFF_XL);
    float* xr      = (float*)(ws + OFF_XR);
    unsigned short* we1h = (unsigned short*)(ws + OFF_WE1H);
    unsigned short* we1l = (unsigned short*)(ws + OFF_WE1L);
    unsigned short* we2h = (unsigned short*)(ws + OFF_WE2H);
    unsigned short* we2l = (unsigned short*)(ws + OFF_WE2L);
    float* outp    = (float*)d_out;

    // edge_attr mean + We bf16 splits
    ea_colsum_part<<<1024, 256, 0, stream>>>(ea, eapart);
    ea_colsum_final<<<1, 256, 0, stream>>>(eapart, eamean);
    we_split<<<64, 256, 0, stream>>>(g1_We, g2_We, we1h, we1l, we2h, we2l);

    // CSR by destination (self-loops included)
    init_counts<<<(kN + 255) / 256, 256, 0, stream>>>(counts);
    count_edges<<<(kE + 255) / 256, 256, 0, stream>>>(ei, counts);
    scan_kernel<<<1, 1024, 0, stream>>>(counts, offs, cursor);
    scatter_kernel<<<(kE + kN + 255) / 256, 256, 0, stream>>>(ei, cursor, csrsrc, csreid);

    // node embedding
    gemm_bias<128, 64, 32><<<(kN + 31) / 32, 256, 0, stream>>>(x, emb_W, emb_b, h_a, kN);

    // ---- GAT layer 1 ----
    gemm_bias<64, 256, 32><<<(kN + 31) / 32, 256, 0, stream>>>(h_a, g1_Wl, g1_bl, xl, kN);
    gemm_bias<64, 256, 32><<<(kN + 31) / 32, 256, 0, stream>>>(h_a, g1_Wr, g1_br, xr, kN);
    gat_node_kernel<<<4096, 256, 0, stream>>>(xl, xr, ea, eamean, we1h, we1l, g1_att, g1_bias,
                                              offs, csrsrc, csreid, h_b);

    // ---- GAT layer 2 ----
    gemm_bias<64, 256, 32><<<(kN + 31) / 32, 256, 0, stream>>>(h_b, g2_Wl, g2_bl, xl, kN);
    gemm_bias<64, 256, 32><<<(kN + 31) / 32, 256, 0, stream>>>(h_b, g2_Wr, g2_br, xr, kN);
    gat_node_kernel<<<4096, 256, 0, stream>>>(xl, xr, ea, eamean, we2h, we2l, g2_att, g2_bias,
                                              offs, csrsrc, csreid, h_a);

    // ---- edge heads ----
    edge_head<<<kE / 16, 256, 0, stream>>>(h_a, ei, ea, int_W, int_b, imp_W, imp_b, outp);
}

// Round 6
// 785.335 us; speedup vs baseline: 1.3959x; 1.0662x over previous
//
#include <hip/hip_runtime.h>
#include <math.h>

// Problem constants
constexpr int kN = 25000;
constexpr int kE = 400000;
constexpr int kTaug = kE + kN;        // CSR slots incl self-loops = 425000
constexpr int kTp = 425216;           // padded pe plane stride
constexpr int kIntents = 12;

typedef __attribute__((ext_vector_type(8))) short bf16x8s;   // 8 bf16 (4 VGPRs)
typedef __attribute__((ext_vector_type(4))) float f32x4;

__device__ __forceinline__ unsigned short f2bf(float f) {
    unsigned u = __builtin_bit_cast(unsigned, f);
    unsigned r = (u + 0x7FFFu + ((u >> 16) & 1u)) >> 16;     // RNE
    return (unsigned short)r;
}
__device__ __forceinline__ float bf2f(unsigned short h) {
    unsigned u = ((unsigned)h) << 16;
    return __builtin_bit_cast(float, u);
}

// DPP-based add from permuted lane (VALU pipe, replaces ds_swizzle).
// CTRL must be a compile-time constant -> template parameter.
template<int CTRL>
__device__ __forceinline__ float dpp_add(float x) {
    int xi = __builtin_bit_cast(int, x);
    int yi = __builtin_amdgcn_update_dpp(0, xi, CTRL, 0xF, 0xF, true);
    return x + __builtin_bit_cast(float, yi);
}

// ---------------- workspace layout (256B aligned) ----------------
constexpr size_t OFF_EAPART = 0;          // 1024*32 f32 = 131072
constexpr size_t OFF_EAMEAN = 131072;     // 32 f32 (pad 256)
constexpr size_t OFF_COUNTS = 131328;     // N i32
constexpr size_t OFF_OFFS   = 231424;     // N+1 i32
constexpr size_t OFF_CURSOR = 331520;     // N i32
constexpr size_t OFF_CSRSRC = 431616;     // Taug i32
constexpr size_t OFF_CSREID = 2131712;    // Taug i32
constexpr size_t OFF_CSRDST = 3831808;    // Taug i32
constexpr size_t OFF_PE     = 5531904;    // 4*kTp f32 = 6803456
constexpr size_t OFF_HA     = 12335360;   // N*64 f32
constexpr size_t OFF_HB     = 18735360;   // N*64 f32
constexpr size_t OFF_XL     = 25135360;   // N*256 f32
constexpr size_t OFF_XR     = 50735360;   // N*256 f32
constexpr size_t OFF_WE1H   = 76335360;   // 32*256 u16
constexpr size_t OFF_WE1L   = 76351744;
constexpr size_t OFF_WE2H   = 76368128;
constexpr size_t OFF_WE2L   = 76384512;   // end ~76.4 MB

// ---------------- edge_attr column mean ----------------
__global__ __launch_bounds__(256) void ea_colsum_part(const float* __restrict__ ea,
                                                      float* __restrict__ part)
{
    __shared__ float lds[256];
    const int tid = threadIdx.x;
    const int k = tid & 31, g = tid >> 5;
    float acc = 0.f;
    for (int r = blockIdx.x * 8 + g; r < kE; r += gridDim.x * 8)
        acc += ea[(size_t)r * 32 + k];
    lds[tid] = acc; __syncthreads();
    if (tid < 128) lds[tid] += lds[tid + 128]; __syncthreads();
    if (tid < 64)  lds[tid] += lds[tid + 64];  __syncthreads();
    if (tid < 32)  part[blockIdx.x * 32 + k] = lds[tid] + lds[tid + 32];
}

__global__ __launch_bounds__(256) void ea_colsum_final(const float* __restrict__ part,
                                                       float* __restrict__ ea_mean)
{
    __shared__ float lds[256];
    const int tid = threadIdx.x;
    const int k = tid & 31, g = tid >> 5;
    float acc = 0.f;
    for (int p = g; p < 1024; p += 8) acc += part[p * 32 + k];
    lds[tid] = acc; __syncthreads();
    if (tid < 128) lds[tid] += lds[tid + 128]; __syncthreads();
    if (tid < 64)  lds[tid] += lds[tid + 64];  __syncthreads();
    if (tid < 32)  ea_mean[k] = (lds[tid] + lds[tid + 32]) * (1.0f / (float)kE);
}

// ---------------- We -> bf16 hi/lo split (both layers) ----------------
__global__ __launch_bounds__(256) void we_split(const float* __restrict__ W1,
                                                const float* __restrict__ W2,
                                                unsigned short* __restrict__ h1,
                                                unsigned short* __restrict__ l1,
                                                unsigned short* __restrict__ h2,
                                                unsigned short* __restrict__ l2)
{
    const int b = blockIdx.x, tid = threadIdx.x;
    const int k = b & 31;
    const float* W = (b < 32) ? W1 : W2;
    unsigned short* H = (b < 32) ? h1 : h2;
    unsigned short* L = (b < 32) ? l1 : l2;
    const float f = W[k * 256 + tid];
    const unsigned short hb = f2bf(f);
    H[k * 256 + tid] = hb;
    L[k * 256 + tid] = f2bf(f - bf2f(hb));
}

// ---------------- CSR build ----------------
__global__ __launch_bounds__(256) void init_counts(int* __restrict__ counts)
{
    int i = blockIdx.x * 256 + threadIdx.x;
    if (i < kN) counts[i] = 1;   // self-loop pre-counted
}

__global__ __launch_bounds__(256) void count_edges(const int* __restrict__ ei,
                                                   int* __restrict__ counts)
{
    int e = blockIdx.x * 256 + threadIdx.x;
    if (e < kE) atomicAdd(&counts[ei[kE + e]], 1);
}

__global__ __launch_bounds__(1024) void scan_kernel(const int* __restrict__ counts,
                                                    int* __restrict__ offsets,
                                                    int* __restrict__ cursor)
{
    __shared__ int lds[1024];
    const int tid = threadIdx.x;
    const int base = tid * 25;
    int local = 0;
#pragma unroll 5
    for (int i = 0; i < 25; i++) {
        int idx = base + i;
        if (idx < kN) local += counts[idx];
    }
    lds[tid] = local; __syncthreads();
    for (int d = 1; d < 1024; d <<= 1) {
        int t = (tid >= d) ? lds[tid - d] : 0;
        __syncthreads();
        lds[tid] += t;
        __syncthreads();
    }
    int run = lds[tid] - local;   // exclusive prefix
    for (int i = 0; i < 25; i++) {
        int idx = base + i;
        if (idx < kN) {
            offsets[idx] = run;
            cursor[idx]  = run;
            run += counts[idx];
        }
    }
    if (tid == 1023) offsets[kN] = lds[1023];
}

__global__ __launch_bounds__(256) void scatter_kernel(const int* __restrict__ ei,
                                                      int* __restrict__ cursor,
                                                      int* __restrict__ csr_src,
                                                      int* __restrict__ csr_eid,
                                                      int* __restrict__ csr_dst)
{
    int gid = blockIdx.x * 256 + threadIdx.x;
    if (gid < kE) {
        int s = ei[gid];
        int d = ei[kE + gid];
        int p = atomicAdd(&cursor[d], 1);
        csr_src[p] = s;
        csr_eid[p] = gid;
        csr_dst[p] = d;
    } else if (gid < kE + kN) {
        int n = gid - kE;
        int p = atomicAdd(&cursor[n], 1);
        csr_src[p] = n;
        csr_eid[p] = kE;   // sentinel: self-loop
        csr_dst[p] = n;
    }
}

// ---------------- small dense GEMM: out[M,KO] = A[M,KI]@W[KI,KO] + b ----------------
template<int KI, int KO, int RPB>
__global__ __launch_bounds__(256) void gemm_bias(const float* __restrict__ A,
                                                 const float* __restrict__ W,
                                                 const float* __restrict__ bias,
                                                 float* __restrict__ out, int M)
{
    constexpr int CG  = 256 / KO;   // column groups
    constexpr int RPT = RPB / CG;   // rows per thread
    __shared__ __align__(16) float a_lds[RPB * KI];
    const int tid = threadIdx.x;
    const int col = tid % KO;
    const int g   = tid / KO;
    const int row0 = blockIdx.x * RPB;

    const float4* Ab = (const float4*)(A + (size_t)row0 * KI);
    float4* L4 = (float4*)a_lds;
    constexpr int ELEM4 = RPB * KI / 4;
    for (int i = tid; i < ELEM4; i += 256) {
        int r = (i * 4) / KI;
        float4 v = make_float4(0.f, 0.f, 0.f, 0.f);
        if (row0 + r < M) v = Ab[i];
        L4[i] = v;
    }
    __syncthreads();

    float acc[RPT];
#pragma unroll
    for (int r = 0; r < RPT; r++) acc[r] = 0.f;
    const float* arow = a_lds + (size_t)(g * RPT) * KI;
    for (int k0 = 0; k0 < KI; k0 += 4) {
        float w0 = W[(k0 + 0) * KO + col];
        float w1 = W[(k0 + 1) * KO + col];
        float w2 = W[(k0 + 2) * KO + col];
        float w3 = W[(k0 + 3) * KO + col];
#pragma unroll
        for (int r = 0; r < RPT; r++) {
            const float4 a = *(const float4*)(arow + r * KI + k0);
            acc[r] += a.x * w0 + a.y * w1 + a.z * w2 + a.w * w3;
        }
    }
    const float bv = bias[col];
#pragma unroll
    for (int r = 0; r < RPT; r++) {
        int row = row0 + g * RPT + r;
        if (row < M) out[(size_t)row * KO + col] = acc[r] + bv;
    }
}

// ---------------- Pass 1: per-edge attention weights (dense 32-edge tiles) ----------------
// block = 256 threads = 4 waves (head = wave), one 32-edge CSR tile per block.
// pe_out[h][slot] = exp(logit) (unshifted; softmax shift-invariant, |logit| << 88).
__global__ __launch_bounds__(256) void edge_logit_kernel(
    const float* __restrict__ xl, const float* __restrict__ xr,
    const float* __restrict__ ea, const float* __restrict__ eamean,
    const unsigned short* __restrict__ weh, const unsigned short* __restrict__ wel,
    const float* __restrict__ att,
    const int* __restrict__ csr_src, const int* __restrict__ csr_dst,
    const int* __restrict__ csr_eid, float* __restrict__ pe_out)
{
    constexpr int ROWS = 40;                       // padded ea row (shorts), 80B
    constexpr int EPP  = 257;                      // padded ep row (floats), 16-edge half
    __shared__ __align__(16) unsigned short ea_hi[32 * ROWS];
    __shared__ __align__(16) unsigned short ea_lo[32 * ROWS];
    __shared__ __align__(16) float ep_lds[16 * EPP];
    __shared__ int s_src[32], s_dst[32];
    const int tid  = threadIdx.x;
    const int w    = tid >> 6;
    const int lane = tid & 63;
    const int b0   = blockIdx.x * 32;
    const int cnt  = min(32, kTaug - b0);

    // B fragments (We hi/lo): col = lane&15, k = (lane>>4)*8 + j
    bf16x8s bh[4], bl[4];
#pragma unroll
    for (int nt = 0; nt < 4; nt++) {
        const int c = w * 64 + nt * 16 + (lane & 15);
        const int k0 = (lane >> 4) * 8;
#pragma unroll
        for (int j = 0; j < 8; j++) {
            bh[nt][j] = (short)weh[(k0 + j) * 256 + c];
            bl[nt][j] = (short)wel[(k0 + j) * 256 + c];
        }
    }
    const float att_r = att[tid];
    const int aoff = (lane & 15) * ROWS + (lane >> 4) * 8;

    if (tid < cnt) {
        s_src[tid] = csr_src[b0 + tid];
        s_dst[tid] = csr_dst[b0 + tid];
    }
    {   // stage ea rows as bf16 hi/lo: 8 threads/edge
        const int j = tid >> 3, q = tid & 7;
        if (j < cnt) {
            const int eid = csr_eid[b0 + j];
            const float4* srcp = (eid < kE) ? (const float4*)(ea + (size_t)eid * 32)
                                            : (const float4*)eamean;
            const float4 f = srcp[q];
            const unsigned short h0 = f2bf(f.x), h1 = f2bf(f.y),
                                 h2 = f2bf(f.z), h3 = f2bf(f.w);
            const unsigned short g0 = f2bf(f.x - bf2f(h0)), g1 = f2bf(f.y - bf2f(h1)),
                                 g2 = f2bf(f.z - bf2f(h2)), g3 = f2bf(f.w - bf2f(h3));
            const unsigned long long ph =
                (unsigned long long)h0 | ((unsigned long long)h1 << 16) |
                ((unsigned long long)h2 << 32) | ((unsigned long long)h3 << 48);
            const unsigned long long pl =
                (unsigned long long)g0 | ((unsigned long long)g1 << 16) |
                ((unsigned long long)g2 << 32) | ((unsigned long long)g3 << 48);
            *(unsigned long long*)&ea_hi[j * ROWS + q * 4] = ph;
            *(unsigned long long*)&ea_lo[j * ROWS + q * 4] = pl;
        }
    }
    __syncthreads();

    // MFMA: ep[32][256] = ea @ We (3-product split-bf16), both row halves
    f32x4 accA[4], accB[4];
    {
        const bf16x8s ah0 = *(const bf16x8s*)&ea_hi[aoff];
        const bf16x8s ah1 = *(const bf16x8s*)&ea_hi[16 * ROWS + aoff];
        const bf16x8s al0 = *(const bf16x8s*)&ea_lo[aoff];
        const bf16x8s al1 = *(const bf16x8s*)&ea_lo[16 * ROWS + aoff];
#pragma unroll
        for (int nt = 0; nt < 4; nt++) {
            f32x4 a0 = {0.f, 0.f, 0.f, 0.f};
            a0 = __builtin_amdgcn_mfma_f32_16x16x32_bf16(ah0, bh[nt], a0, 0, 0, 0);
            a0 = __builtin_amdgcn_mfma_f32_16x16x32_bf16(ah0, bl[nt], a0, 0, 0, 0);
            a0 = __builtin_amdgcn_mfma_f32_16x16x32_bf16(al0, bh[nt], a0, 0, 0, 0);
            accA[nt] = a0;
            f32x4 a1 = {0.f, 0.f, 0.f, 0.f};
            a1 = __builtin_amdgcn_mfma_f32_16x16x32_bf16(ah1, bh[nt], a1, 0, 0, 0);
            a1 = __builtin_amdgcn_mfma_f32_16x16x32_bf16(ah1, bl[nt], a1, 0, 0, 0);
            a1 = __builtin_amdgcn_mfma_f32_16x16x32_bf16(al1, bh[nt], a1, 0, 0, 0);
            accB[nt] = a1;
        }
    }

    const int cbase = w * 64 + (lane & 15);
    const int rbase = (lane >> 4) * 4;
    float keep = 0.f;                              // pe for edge==lane

    const int c0 = min(cnt, 16);
    const int c1 = cnt - c0;

#pragma unroll
    for (int half = 0; half < 2; half++) {
        // scatter this half's ep into LDS
#pragma unroll
        for (int nt = 0; nt < 4; nt++) {
            const f32x4 a = half ? accB[nt] : accA[nt];
            const int cc = cbase + nt * 16;
#pragma unroll
            for (int r = 0; r < 4; r++)
                ep_lds[(rbase + r) * EPP + cc] = a[r];
        }
        __syncthreads();

        const int ebase = half * 16;
        const int ecnt  = half ? c1 : c0;
        int i = 0;
        for (; i + 8 <= ecnt; i += 8) {
            const int e0 = ebase + i;
            float xls[8], c[8];
            int sv[8], dv[8];
#pragma unroll
            for (int u = 0; u < 8; u++) { sv[u] = s_src[e0 + u]; dv[u] = s_dst[e0 + u]; }
#pragma unroll
            for (int u = 0; u < 8; u++) xls[u] = xl[sv[u] * 256 + tid];
            float xrr[8];
#pragma unroll
            for (int u = 0; u < 8; u++) xrr[u] = xr[dv[u] * 256 + tid];
#pragma unroll
            for (int u = 0; u < 8; u++) {
                float v = xls[u] + xrr[u] + ep_lds[((e0 + u) & 15) * EPP + tid];
                v = fmaxf(v, 0.f) + 0.2f * fminf(v, 0.f);   // leaky_relu 0.2
                c[u] = att_r * v;
            }
            // interleaved reduce: 4 DPP (VALU) + 2 shfl (DS)
#pragma unroll
            for (int u = 0; u < 8; u++) c[u] = dpp_add<0xB1>(c[u]);   // quad_perm xor1
#pragma unroll
            for (int u = 0; u < 8; u++) c[u] = dpp_add<0x4E>(c[u]);   // quad_perm xor2
#pragma unroll
            for (int u = 0; u < 8; u++) c[u] = dpp_add<0x124>(c[u]);  // row_ror:4
#pragma unroll
            for (int u = 0; u < 8; u++) c[u] = dpp_add<0x128>(c[u]);  // row_ror:8
#pragma unroll
            for (int u = 0; u < 8; u++) c[u] += __shfl_xor(c[u], 16);
#pragma unroll
            for (int u = 0; u < 8; u++) c[u] += __shfl_xor(c[u], 32);
#pragma unroll
            for (int u = 0; u < 8; u++) {
                const float pe = __expf(c[u]);
                keep = (lane == e0 + u) ? pe : keep;
            }
        }
        for (; i < ecnt; i++) {                    // tail
            const int e = ebase + i;
            const float xls = xl[s_src[e] * 256 + tid];
            const float xrr = xr[s_dst[e] * 256 + tid];
            float v = xls + xrr + ep_lds[(e & 15) * EPP + tid];
            v = fmaxf(v, 0.f) + 0.2f * fminf(v, 0.f);
            float cc = att_r * v;
            cc = dpp_add<0xB1>(cc);
            cc = dpp_add<0x4E>(cc);
            cc = dpp_add<0x124>(cc);
            cc = dpp_add<0x128>(cc);
            cc += __shfl_xor(cc, 16);
            cc += __shfl_xor(cc, 32);
            const float pe = __expf(cc);
            keep = (lane == e) ? pe : keep;
        }
        __syncthreads();                           // ep_lds reuse / uniform exit
    }

    if (lane < cnt) pe_out[w * kTp + b0 + lane] = keep;   // coalesced per wave
}

// ---------------- Pass 2: per-node aggregate ----------------
// block = node; wave = head; lane = channel. den/acc streamed, no shuffles.
__global__ __launch_bounds__(256) void gat_aggr_kernel(
    const float* __restrict__ xl, const float* __restrict__ pe,
    const int* __restrict__ csr_src, const int* __restrict__ offsets,
    const float* __restrict__ gbias, float* __restrict__ h_out)
{
    __shared__ float red[256];
    const int tid = threadIdx.x;
    const int w = tid >> 6;
    const int n = blockIdx.x;
    const int o0 = offsets[n], o1 = offsets[n + 1];
    const float* pep = pe + (size_t)w * kTp;

    float den = 0.f, acc = 0.f;
    int i = o0;
    for (; i + 8 <= o1; i += 8) {
        float pv[8], xv[8];
        int sv[8];
#pragma unroll
        for (int u = 0; u < 8; u++) pv[u] = pep[i + u];        // broadcast loads
#pragma unroll
        for (int u = 0; u < 8; u++) sv[u] = csr_src[i + u];
#pragma unroll
        for (int u = 0; u < 8; u++) xv[u] = xl[sv[u] * 256 + tid];  // 8 gathers in flight
#pragma unroll
        for (int u = 0; u < 8; u++) {
            den += pv[u];
            acc += pv[u] * xv[u];
        }
    }
    for (; i < o1; i++) {
        const float p = pep[i];
        den += p;
        acc += p * xl[csr_src[i] * 256 + tid];
    }
    red[tid] = acc / den;
    __syncthreads();
    if (tid < 64) {
        float sres = red[tid] + red[tid + 64] + red[tid + 128] + red[tid + 192];
        h_out[n * 64 + tid] = fmaxf(0.25f * sres + gbias[tid], 0.f);
    }
}

// ---------------- final edge heads: intent logits + importance ----------------
__global__ __launch_bounds__(256) void edge_head(
    const float* __restrict__ h, const int* __restrict__ ei,
    const float* __restrict__ ea, const float* __restrict__ intW,
    const float* __restrict__ intb, const float* __restrict__ impW,
    const float* __restrict__ impb, float* __restrict__ out)
{
    __shared__ __align__(16) float rep[16 * 164];
    __shared__ __align__(16) float W13[13 * 164];
    __shared__ int s_src[16], s_dst[16];
    const int tid = threadIdx.x;
    const int e0 = blockIdx.x * 16;

    for (int i = tid; i < 13 * 160; i += 256) {
        int k = i / 13, c = i % 13;
        W13[c * 164 + k] = (c < 12) ? intW[k * 12 + c] : impW[k];
    }
    if (tid < 16) {
        s_src[tid] = ei[e0 + tid];
        s_dst[tid] = ei[kE + e0 + tid];
    }
    __syncthreads();

    for (int i = tid; i < 16 * 160; i += 256) {
        int j = i / 160, k = i % 160;
        float v;
        if (k < 64)       v = h[(size_t)s_src[j] * 64 + k];
        else if (k < 128) v = h[(size_t)s_dst[j] * 64 + (k - 64)];
        else              v = ea[(size_t)(e0 + j) * 32 + (k - 128)];
        rep[j * 164 + k] = fmaxf(v, 0.f);   // relu(concat)
    }
    __syncthreads();

    if (tid < 16 * 13) {
        int j = tid / 13, c = tid % 13;
        const float4* rp = (const float4*)(rep + j * 164);
        const float4* wp = (const float4*)(W13 + c * 164);
        float acc = 0.f;
#pragma unroll 8
        for (int q = 0; q < 40; q++) {
            float4 a = rp[q], w = wp[q];
            acc += a.x * w.x + a.y * w.y + a.z * w.z + a.w * w.w;
        }
        int eg = e0 + j;
        if (c < 12) {
            out[(size_t)eg * 12 + c] = acc + intb[c];
        } else {
            float z = acc + impb[0];
            out[(size_t)kE * 12 + eg] = 1.f / (1.f + __expf(-z));
        }
    }
}

// ---------------- launch ----------------
extern "C" void kernel_launch(void* const* d_in, const int* in_sizes, int n_in,
                              void* d_out, int out_size, void* d_ws, size_t ws_size,
                              hipStream_t stream)
{
    (void)in_sizes; (void)n_in; (void)out_size; (void)ws_size;

    const float* x      = (const float*)d_in[0];
    const int*   ei     = (const int*)d_in[1];
    const float* ea     = (const float*)d_in[2];
    const float* emb_W  = (const float*)d_in[3];
    const float* emb_b  = (const float*)d_in[4];
    const float* g1_Wl  = (const float*)d_in[5];
    const float* g1_bl  = (const float*)d_in[6];
    const float* g1_Wr  = (const float*)d_in[7];
    const float* g1_br  = (const float*)d_in[8];
    const float* g1_We  = (const float*)d_in[9];
    const float* g1_att = (const float*)d_in[10];
    const float* g1_bias= (const float*)d_in[11];
    const float* g2_Wl  = (const float*)d_in[12];
    const float* g2_bl  = (const float*)d_in[13];
    const float* g2_Wr  = (const float*)d_in[14];
    const float* g2_br  = (const float*)d_in[15];
    const float* g2_We  = (const float*)d_in[16];
    const float* g2_att = (const float*)d_in[17];
    const float* g2_bias= (const float*)d_in[18];
    const float* int_W  = (const float*)d_in[19];
    const float* int_b  = (const float*)d_in[20];
    const float* imp_W  = (const float*)d_in[21];
    const float* imp_b  = (const float*)d_in[22];

    char* ws = (char*)d_ws;
    float* eapart  = (float*)(ws + OFF_EAPART);
    float* eamean  = (float*)(ws + OFF_EAMEAN);
    int*   counts  = (int*)  (ws + OFF_COUNTS);
    int*   offs    = (int*)  (ws + OFF_OFFS);
    int*   cursor  = (int*)  (ws + OFF_CURSOR);
    int*   csrsrc  = (int*)  (ws + OFF_CSRSRC);
    int*   csreid  = (int*)  (ws + OFF_CSREID);
    int*   csrdst  = (int*)  (ws + OFF_CSRDST);
    float* pe      = (float*)(ws + OFF_PE);
    float* h_a     = (float*)(ws + OFF_HA);
    float* h_b     = (float*)(ws + OFF_HB);
    float* xl      = (float*)(ws + OFF_XL);
    float* xr      = (float*)(ws + OFF_XR);
    unsigned short* we1h = (unsigned short*)(ws + OFF_WE1H);
    unsigned short* we1l = (unsigned short*)(ws + OFF_WE1L);
    unsigned short* we2h = (unsigned short*)(ws + OFF_WE2H);
    unsigned short* we2l = (unsigned short*)(ws + OFF_WE2L);
    float* outp    = (float*)d_out;

    constexpr int NT = (kTaug + 31) / 32;   // 13282 edge tiles

    // edge_attr mean + We bf16 splits
    ea_colsum_part<<<1024, 256, 0, stream>>>(ea, eapart);
    ea_colsum_final<<<1, 256, 0, stream>>>(eapart, eamean);
    we_split<<<64, 256, 0, stream>>>(g1_We, g2_We, we1h, we1l, we2h, we2l);

    // CSR by destination (self-loops included)
    init_counts<<<(kN + 255) / 256, 256, 0, stream>>>(counts);
    count_edges<<<(kE + 255) / 256, 256, 0, stream>>>(ei, counts);
    scan_kernel<<<1, 1024, 0, stream>>>(counts, offs, cursor);
    scatter_kernel<<<(kE + kN + 255) / 256, 256, 0, stream>>>(ei, cursor, csrsrc, csreid, csrdst);

    // node embedding
    gemm_bias<128, 64, 32><<<(kN + 31) / 32, 256, 0, stream>>>(x, emb_W, emb_b, h_a, kN);

    // ---- GAT layer 1 ----
    gemm_bias<64, 256, 32><<<(kN + 31) / 32, 256, 0, stream>>>(h_a, g1_Wl, g1_bl, xl, kN);
    gemm_bias<64, 256, 32><<<(kN + 31) / 32, 256, 0, stream>>>(h_a, g1_Wr, g1_br, xr, kN);
    edge_logit_kernel<<<NT, 256, 0, stream>>>(xl, xr, ea, eamean, we1h, we1l, g1_att,
                                              csrsrc, csrdst, csreid, pe);
    gat_aggr_kernel<<<kN, 256, 0, stream>>>(xl, pe, csrsrc, offs, g1_bias, h_b);

    // ---- GAT layer 2 ----
    gemm_bias<64, 256, 32><<<(kN + 31) / 32, 256, 0, stream>>>(h_b, g2_Wl, g2_bl, xl, kN);
    gemm_bias<64, 256, 32><<<(kN + 31) / 32, 256, 0, stream>>>(h_b, g2_Wr, g2_br, xr, kN);
    edge_logit_kernel<<<NT, 256, 0, stream>>>(xl, xr, ea, eamean, we2h, we2l, g2_att,
                                              csrsrc, csrdst, csreid, pe);
    gat_aggr_kernel<<<kN, 256, 0, stream>>>(xl, pe, csrsrc, offs, g2_bias, h_a);

    // ---- edge heads ----
    edge_head<<<kE / 16, 256, 0, stream>>>(h_a, ei, ea, int_W, int_b, imp_W, imp_b, outp);
}

// Round 7
// 677.970 us; speedup vs baseline: 1.6170x; 1.1584x over previous
//
#include <hip/hip_runtime.h>
#include <math.h>

// Problem constants
constexpr int kN = 25000;
constexpr int kE = 400000;
constexpr int kTaug = kE + kN;        // CSR slots incl self-loops = 425000
constexpr int kTp = 425216;           // padded pe plane stride
constexpr int kIntents = 12;

typedef __attribute__((ext_vector_type(8))) short bf16x8s;   // 8 bf16 (4 VGPRs)
typedef __attribute__((ext_vector_type(4))) float f32x4;

__device__ __forceinline__ unsigned short f2bf(float f) {
    unsigned u = __builtin_bit_cast(unsigned, f);
    unsigned r = (u + 0x7FFFu + ((u >> 16) & 1u)) >> 16;     // RNE
    return (unsigned short)r;
}
__device__ __forceinline__ float bf2f(unsigned short h) {
    unsigned u = ((unsigned)h) << 16;
    return __builtin_bit_cast(float, u);
}

// DPP-based add from permuted lane (VALU pipe, replaces ds_swizzle).
template<int CTRL>
__device__ __forceinline__ float dpp_add(float x) {
    int xi = __builtin_bit_cast(int, x);
    int yi = __builtin_amdgcn_update_dpp(0, xi, CTRL, 0xF, 0xF, true);
    return x + __builtin_bit_cast(float, yi);
}

// ---------------- workspace layout (256B aligned) ----------------
constexpr size_t OFF_EAPART = 0;          // 1024*32 f32 = 131072
constexpr size_t OFF_EAMEAN = 131072;     // 32 f32 (pad 256)
constexpr size_t OFF_COUNTS = 131328;     // N i32
constexpr size_t OFF_OFFS   = 231424;     // N+1 i32
constexpr size_t OFF_CURSOR = 331520;     // N i32
constexpr size_t OFF_CSRSRC = 431616;     // Taug i32
constexpr size_t OFF_CSREID = 2131712;    // Taug i32
constexpr size_t OFF_CSRDST = 3831808;    // Taug i32
constexpr size_t OFF_PE     = 5531904;    // 4*kTp f32 = 6803456 (reused as P after aggr2)
constexpr size_t OFF_HA     = 12335360;   // N*64 f32
constexpr size_t OFF_HB     = 18735360;   // N*64 f32
constexpr size_t OFF_XL     = 25135360;   // N*256 f32
constexpr size_t OFF_XR     = 50735360;   // N*256 f32
constexpr size_t OFF_WE1H   = 76335360;   // 32*256 u16
constexpr size_t OFF_WE1L   = 76351744;
constexpr size_t OFF_WE2H   = 76368128;
constexpr size_t OFF_WE2L   = 76384512;   // end ~76.4 MB

// ---------------- edge_attr column mean ----------------
__global__ __launch_bounds__(256) void ea_colsum_part(const float* __restrict__ ea,
                                                      float* __restrict__ part)
{
    __shared__ float lds[256];
    const int tid = threadIdx.x;
    const int k = tid & 31, g = tid >> 5;
    float acc = 0.f;
    for (int r = blockIdx.x * 8 + g; r < kE; r += gridDim.x * 8)
        acc += ea[(size_t)r * 32 + k];
    lds[tid] = acc; __syncthreads();
    if (tid < 128) lds[tid] += lds[tid + 128]; __syncthreads();
    if (tid < 64)  lds[tid] += lds[tid + 64];  __syncthreads();
    if (tid < 32)  part[blockIdx.x * 32 + k] = lds[tid] + lds[tid + 32];
}

__global__ __launch_bounds__(256) void ea_colsum_final(const float* __restrict__ part,
                                                       float* __restrict__ ea_mean)
{
    __shared__ float lds[256];
    const int tid = threadIdx.x;
    const int k = tid & 31, g = tid >> 5;
    float acc = 0.f;
    for (int p = g; p < 1024; p += 8) acc += part[p * 32 + k];
    lds[tid] = acc; __syncthreads();
    if (tid < 128) lds[tid] += lds[tid + 128]; __syncthreads();
    if (tid < 64)  lds[tid] += lds[tid + 64];  __syncthreads();
    if (tid < 32)  ea_mean[k] = (lds[tid] + lds[tid + 32]) * (1.0f / (float)kE);
}

// ---------------- We -> bf16 hi/lo split (both layers) ----------------
__global__ __launch_bounds__(256) void we_split(const float* __restrict__ W1,
                                                const float* __restrict__ W2,
                                                unsigned short* __restrict__ h1,
                                                unsigned short* __restrict__ l1,
                                                unsigned short* __restrict__ h2,
                                                unsigned short* __restrict__ l2)
{
    const int b = blockIdx.x, tid = threadIdx.x;
    const int k = b & 31;
    const float* W = (b < 32) ? W1 : W2;
    unsigned short* H = (b < 32) ? h1 : h2;
    unsigned short* L = (b < 32) ? l1 : l2;
    const float f = W[k * 256 + tid];
    const unsigned short hb = f2bf(f);
    H[k * 256 + tid] = hb;
    L[k * 256 + tid] = f2bf(f - bf2f(hb));
}

// ---------------- CSR build ----------------
__global__ __launch_bounds__(256) void init_counts(int* __restrict__ counts)
{
    int i = blockIdx.x * 256 + threadIdx.x;
    if (i < kN) counts[i] = 1;   // self-loop pre-counted
}

__global__ __launch_bounds__(256) void count_edges(const int* __restrict__ ei,
                                                   int* __restrict__ counts)
{
    int e = blockIdx.x * 256 + threadIdx.x;
    if (e < kE) atomicAdd(&counts[ei[kE + e]], 1);
}

__global__ __launch_bounds__(1024) void scan_kernel(const int* __restrict__ counts,
                                                    int* __restrict__ offsets,
                                                    int* __restrict__ cursor)
{
    __shared__ int lds[1024];
    const int tid = threadIdx.x;
    const int base = tid * 25;
    int local = 0;
#pragma unroll 5
    for (int i = 0; i < 25; i++) {
        int idx = base + i;
        if (idx < kN) local += counts[idx];
    }
    lds[tid] = local; __syncthreads();
    for (int d = 1; d < 1024; d <<= 1) {
        int t = (tid >= d) ? lds[tid - d] : 0;
        __syncthreads();
        lds[tid] += t;
        __syncthreads();
    }
    int run = lds[tid] - local;   // exclusive prefix
    for (int i = 0; i < 25; i++) {
        int idx = base + i;
        if (idx < kN) {
            offsets[idx] = run;
            cursor[idx]  = run;
            run += counts[idx];
        }
    }
    if (tid == 1023) offsets[kN] = lds[1023];
}

__global__ __launch_bounds__(256) void scatter_kernel(const int* __restrict__ ei,
                                                      int* __restrict__ cursor,
                                                      int* __restrict__ csr_src,
                                                      int* __restrict__ csr_eid,
                                                      int* __restrict__ csr_dst)
{
    int gid = blockIdx.x * 256 + threadIdx.x;
    if (gid < kE) {
        int s = ei[gid];
        int d = ei[kE + gid];
        int p = atomicAdd(&cursor[d], 1);
        csr_src[p] = s;
        csr_eid[p] = gid;
        csr_dst[p] = d;
    } else if (gid < kE + kN) {
        int n = gid - kE;
        int p = atomicAdd(&cursor[n], 1);
        csr_src[p] = n;
        csr_eid[p] = kE;   // sentinel: self-loop
        csr_dst[p] = n;
    }
}

// ---------------- small dense GEMM: out[M,KO] = A[M,KI]@W[KI,KO] + b ----------------
template<int KI, int KO, int RPB>
__global__ __launch_bounds__(256) void gemm_bias(const float* __restrict__ A,
                                                 const float* __restrict__ W,
                                                 const float* __restrict__ bias,
                                                 float* __restrict__ out, int M)
{
    constexpr int CG  = 256 / KO;   // column groups
    constexpr int RPT = RPB / CG;   // rows per thread
    __shared__ __align__(16) float a_lds[RPB * KI];
    const int tid = threadIdx.x;
    const int col = tid % KO;
    const int g   = tid / KO;
    const int row0 = blockIdx.x * RPB;

    const float4* Ab = (const float4*)(A + (size_t)row0 * KI);
    float4* L4 = (float4*)a_lds;
    constexpr int ELEM4 = RPB * KI / 4;
    for (int i = tid; i < ELEM4; i += 256) {
        int r = (i * 4) / KI;
        float4 v = make_float4(0.f, 0.f, 0.f, 0.f);
        if (row0 + r < M) v = Ab[i];
        L4[i] = v;
    }
    __syncthreads();

    float acc[RPT];
#pragma unroll
    for (int r = 0; r < RPT; r++) acc[r] = 0.f;
    const float* arow = a_lds + (size_t)(g * RPT) * KI;
    for (int k0 = 0; k0 < KI; k0 += 4) {
        float w0 = W[(k0 + 0) * KO + col];
        float w1 = W[(k0 + 1) * KO + col];
        float w2 = W[(k0 + 2) * KO + col];
        float w3 = W[(k0 + 3) * KO + col];
#pragma unroll
        for (int r = 0; r < RPT; r++) {
            const float4 a = *(const float4*)(arow + r * KI + k0);
            acc[r] += a.x * w0 + a.y * w1 + a.z * w2 + a.w * w3;
        }
    }
    const float bv = bias[col];
#pragma unroll
    for (int r = 0; r < RPT; r++) {
        int row = row0 + g * RPT + r;
        if (row < M) out[(size_t)row * KO + col] = acc[r] + bv;
    }
}

// ---------------- Pass 1: per-edge attention weights (dense 32-edge tiles) ----------------
__global__ __launch_bounds__(256) void edge_logit_kernel(
    const float* __restrict__ xl, const float* __restrict__ xr,
    const float* __restrict__ ea, const float* __restrict__ eamean,
    const unsigned short* __restrict__ weh, const unsigned short* __restrict__ wel,
    const float* __restrict__ att,
    const int* __restrict__ csr_src, const int* __restrict__ csr_dst,
    const int* __restrict__ csr_eid, float* __restrict__ pe_out)
{
    constexpr int ROWS = 40;                       // padded ea row (shorts), 80B
    constexpr int EPP  = 257;                      // padded ep row (floats), 16-edge half
    __shared__ __align__(16) unsigned short ea_hi[32 * ROWS];
    __shared__ __align__(16) unsigned short ea_lo[32 * ROWS];
    __shared__ __align__(16) float ep_lds[16 * EPP];
    __shared__ int s_src[32], s_dst[32];
    const int tid  = threadIdx.x;
    const int w    = tid >> 6;
    const int lane = tid & 63;
    const int b0   = blockIdx.x * 32;
    const int cnt  = min(32, kTaug - b0);

    // B fragments (We hi/lo): col = lane&15, k = (lane>>4)*8 + j
    bf16x8s bh[4], bl[4];
#pragma unroll
    for (int nt = 0; nt < 4; nt++) {
        const int c = w * 64 + nt * 16 + (lane & 15);
        const int k0 = (lane >> 4) * 8;
#pragma unroll
        for (int j = 0; j < 8; j++) {
            bh[nt][j] = (short)weh[(k0 + j) * 256 + c];
            bl[nt][j] = (short)wel[(k0 + j) * 256 + c];
        }
    }
    const float att_r = att[tid];
    const int aoff = (lane & 15) * ROWS + (lane >> 4) * 8;

    if (tid < cnt) {
        s_src[tid] = csr_src[b0 + tid];
        s_dst[tid] = csr_dst[b0 + tid];
    }
    {   // stage ea rows as bf16 hi/lo: 8 threads/edge
        const int j = tid >> 3, q = tid & 7;
        if (j < cnt) {
            const int eid = csr_eid[b0 + j];
            const float4* srcp = (eid < kE) ? (const float4*)(ea + (size_t)eid * 32)
                                            : (const float4*)eamean;
            const float4 f = srcp[q];
            const unsigned short h0 = f2bf(f.x), h1 = f2bf(f.y),
                                 h2 = f2bf(f.z), h3 = f2bf(f.w);
            const unsigned short g0 = f2bf(f.x - bf2f(h0)), g1 = f2bf(f.y - bf2f(h1)),
                                 g2 = f2bf(f.z - bf2f(h2)), g3 = f2bf(f.w - bf2f(h3));
            const unsigned long long ph =
                (unsigned long long)h0 | ((unsigned long long)h1 << 16) |
                ((unsigned long long)h2 << 32) | ((unsigned long long)h3 << 48);
            const unsigned long long pl =
                (unsigned long long)g0 | ((unsigned long long)g1 << 16) |
                ((unsigned long long)g2 << 32) | ((unsigned long long)g3 << 48);
            *(unsigned long long*)&ea_hi[j * ROWS + q * 4] = ph;
            *(unsigned long long*)&ea_lo[j * ROWS + q * 4] = pl;
        }
    }
    __syncthreads();

    // MFMA: ep[32][256] = ea @ We (3-product split-bf16), both row halves
    f32x4 accA[4], accB[4];
    {
        const bf16x8s ah0 = *(const bf16x8s*)&ea_hi[aoff];
        const bf16x8s ah1 = *(const bf16x8s*)&ea_hi[16 * ROWS + aoff];
        const bf16x8s al0 = *(const bf16x8s*)&ea_lo[aoff];
        const bf16x8s al1 = *(const bf16x8s*)&ea_lo[16 * ROWS + aoff];
#pragma unroll
        for (int nt = 0; nt < 4; nt++) {
            f32x4 a0 = {0.f, 0.f, 0.f, 0.f};
            a0 = __builtin_amdgcn_mfma_f32_16x16x32_bf16(ah0, bh[nt], a0, 0, 0, 0);
            a0 = __builtin_amdgcn_mfma_f32_16x16x32_bf16(ah0, bl[nt], a0, 0, 0, 0);
            a0 = __builtin_amdgcn_mfma_f32_16x16x32_bf16(al0, bh[nt], a0, 0, 0, 0);
            accA[nt] = a0;
            f32x4 a1 = {0.f, 0.f, 0.f, 0.f};
            a1 = __builtin_amdgcn_mfma_f32_16x16x32_bf16(ah1, bh[nt], a1, 0, 0, 0);
            a1 = __builtin_amdgcn_mfma_f32_16x16x32_bf16(ah1, bl[nt], a1, 0, 0, 0);
            a1 = __builtin_amdgcn_mfma_f32_16x16x32_bf16(al1, bh[nt], a1, 0, 0, 0);
            accB[nt] = a1;
        }
    }

    const int cbase = w * 64 + (lane & 15);
    const int rbase = (lane >> 4) * 4;
    float keep = 0.f;                              // pe for edge==lane

    const int c0 = min(cnt, 16);
    const int c1 = cnt - c0;

#pragma unroll
    for (int half = 0; half < 2; half++) {
#pragma unroll
        for (int nt = 0; nt < 4; nt++) {
            const f32x4 a = half ? accB[nt] : accA[nt];
            const int cc = cbase + nt * 16;
#pragma unroll
            for (int r = 0; r < 4; r++)
                ep_lds[(rbase + r) * EPP + cc] = a[r];
        }
        __syncthreads();

        const int ebase = half * 16;
        const int ecnt  = half ? c1 : c0;
        int i = 0;
        for (; i + 8 <= ecnt; i += 8) {
            const int e0 = ebase + i;
            float xls[8], c[8];
            int sv[8], dv[8];
#pragma unroll
            for (int u = 0; u < 8; u++) { sv[u] = s_src[e0 + u]; dv[u] = s_dst[e0 + u]; }
#pragma unroll
            for (int u = 0; u < 8; u++) xls[u] = xl[sv[u] * 256 + tid];
            float xrr[8];
#pragma unroll
            for (int u = 0; u < 8; u++) xrr[u] = xr[dv[u] * 256 + tid];
#pragma unroll
            for (int u = 0; u < 8; u++) {
                float v = xls[u] + xrr[u] + ep_lds[((e0 + u) & 15) * EPP + tid];
                v = fmaxf(v, 0.f) + 0.2f * fminf(v, 0.f);   // leaky_relu 0.2
                c[u] = att_r * v;
            }
#pragma unroll
            for (int u = 0; u < 8; u++) c[u] = dpp_add<0xB1>(c[u]);
#pragma unroll
            for (int u = 0; u < 8; u++) c[u] = dpp_add<0x4E>(c[u]);
#pragma unroll
            for (int u = 0; u < 8; u++) c[u] = dpp_add<0x124>(c[u]);
#pragma unroll
            for (int u = 0; u < 8; u++) c[u] = dpp_add<0x128>(c[u]);
#pragma unroll
            for (int u = 0; u < 8; u++) c[u] += __shfl_xor(c[u], 16);
#pragma unroll
            for (int u = 0; u < 8; u++) c[u] += __shfl_xor(c[u], 32);
#pragma unroll
            for (int u = 0; u < 8; u++) {
                const float pe = __expf(c[u]);
                keep = (lane == e0 + u) ? pe : keep;
            }
        }
        for (; i < ecnt; i++) {                    // tail
            const int e = ebase + i;
            const float xls = xl[s_src[e] * 256 + tid];
            const float xrr = xr[s_dst[e] * 256 + tid];
            float v = xls + xrr + ep_lds[(e & 15) * EPP + tid];
            v = fmaxf(v, 0.f) + 0.2f * fminf(v, 0.f);
            float cc = att_r * v;
            cc = dpp_add<0xB1>(cc);
            cc = dpp_add<0x4E>(cc);
            cc = dpp_add<0x124>(cc);
            cc = dpp_add<0x128>(cc);
            cc += __shfl_xor(cc, 16);
            cc += __shfl_xor(cc, 32);
            const float pe = __expf(cc);
            keep = (lane == e) ? pe : keep;
        }
        __syncthreads();
    }

    if (lane < cnt) pe_out[w * kTp + b0 + lane] = keep;   // coalesced per wave
}

// ---------------- Pass 2: per-node aggregate ----------------
__global__ __launch_bounds__(256) void gat_aggr_kernel(
    const float* __restrict__ xl, const float* __restrict__ pe,
    const int* __restrict__ csr_src, const int* __restrict__ offsets,
    const float* __restrict__ gbias, float* __restrict__ h_out)
{
    __shared__ float red[256];
    const int tid = threadIdx.x;
    const int w = tid >> 6;
    const int n = blockIdx.x;
    const int o0 = offsets[n], o1 = offsets[n + 1];
    const float* pep = pe + (size_t)w * kTp;

    float den = 0.f, acc = 0.f;
    int i = o0;
    for (; i + 8 <= o1; i += 8) {
        float pv[8], xv[8];
        int sv[8];
#pragma unroll
        for (int u = 0; u < 8; u++) pv[u] = pep[i + u];
#pragma unroll
        for (int u = 0; u < 8; u++) sv[u] = csr_src[i + u];
#pragma unroll
        for (int u = 0; u < 8; u++) xv[u] = xl[sv[u] * 256 + tid];
#pragma unroll
        for (int u = 0; u < 8; u++) {
            den += pv[u];
            acc += pv[u] * xv[u];
        }
    }
    for (; i < o1; i++) {
        const float p = pep[i];
        den += p;
        acc += p * xl[csr_src[i] * 256 + tid];
    }
    red[tid] = acc / den;
    __syncthreads();
    if (tid < 64) {
        float sres = red[tid] + red[tid + 64] + red[tid + 128] + red[tid + 192];
        h_out[n * 64 + tid] = fmaxf(0.25f * sres + gbias[tid], 0.f);
    }
}

// ---------------- node head: P[n][0:16]=h@W13[0:64], P[n][16:32]=h@W13[64:128] ----------------
// (edge_rep@W decomposes: relu(h)=h since h is relu'd; per-node terms precomputed once.)
__global__ __launch_bounds__(256) void node_head_kernel(
    const float* __restrict__ h, const float* __restrict__ intW,
    const float* __restrict__ impW, float* __restrict__ P)
{
    const int tid = threadIdx.x;
    const int w = tid >> 6, lane = tid & 63;
    const int row0 = blockIdx.x * 64 + w * 16;
    const int rr = lane & 15;             // A-row / B-col / C-col
    const int kg = lane >> 4;             // k-group

    // B frags: col-tile 0 = src cols (W rows 0..63), tile 1 = dst cols (rows 64..127)
    bf16x8s Bh[2][2], Bl[2][2];
#pragma unroll
    for (int ct = 0; ct < 2; ct++) {
#pragma unroll
        for (int kk = 0; kk < 2; kk++) {
            const int kbase = ct * 64 + kk * 32 + kg * 8;
#pragma unroll
            for (int j = 0; j < 8; j++) {
                const int k = kbase + j;
                float wv;
                if (rr < 12)       wv = intW[k * 12 + rr];
                else if (rr == 12) wv = impW[k];
                else               wv = 0.f;
                const unsigned short hb = f2bf(wv);
                Bh[ct][kk][j] = (short)hb;
                Bl[ct][kk][j] = (short)f2bf(wv - bf2f(hb));
            }
        }
    }

    // A frags: h rows (clamped), k = kk*32 + kg*8 + j
    const int arow = min(row0 + rr, kN - 1);
    bf16x8s Ah[2], Al[2];
#pragma unroll
    for (int kk = 0; kk < 2; kk++) {
        const float4 f0 = *(const float4*)&h[arow * 64 + kk * 32 + kg * 8];
        const float4 f1 = *(const float4*)&h[arow * 64 + kk * 32 + kg * 8 + 4];
        const float fv[8] = {f0.x, f0.y, f0.z, f0.w, f1.x, f1.y, f1.z, f1.w};
#pragma unroll
        for (int j = 0; j < 8; j++) {
            const unsigned short hb = f2bf(fv[j]);
            Ah[kk][j] = (short)hb;
            Al[kk][j] = (short)f2bf(fv[j] - bf2f(hb));
        }
    }

#pragma unroll
    for (int ct = 0; ct < 2; ct++) {
        f32x4 acc = {0.f, 0.f, 0.f, 0.f};
#pragma unroll
        for (int kk = 0; kk < 2; kk++) {
            acc = __builtin_amdgcn_mfma_f32_16x16x32_bf16(Ah[kk], Bh[ct][kk], acc, 0, 0, 0);
            acc = __builtin_amdgcn_mfma_f32_16x16x32_bf16(Ah[kk], Bl[ct][kk], acc, 0, 0, 0);
            acc = __builtin_amdgcn_mfma_f32_16x16x32_bf16(Al[kk], Bh[ct][kk], acc, 0, 0, 0);
        }
        const int crow0 = kg * 4;
#pragma unroll
        for (int r = 0; r < 4; r++) {
            const int row = row0 + crow0 + r;
            if (row < kN) P[row * 32 + ct * 16 + rr] = acc[r];
        }
    }
}

// ---------------- edge out: Q = relu(ea)@W13[128:160]; out = Q + P_src + P_dst + b ----------------
__global__ __launch_bounds__(256) void edge_out_kernel(
    const float* __restrict__ ea, const int* __restrict__ ei,
    const float* __restrict__ P,
    const float* __restrict__ intW, const float* __restrict__ intb,
    const float* __restrict__ impW, const float* __restrict__ impb,
    float* __restrict__ out)
{
    constexpr int ROWS = 40;
    __shared__ __align__(16) unsigned short ehi[4][16 * ROWS];
    __shared__ __align__(16) unsigned short elo[4][16 * ROWS];
    const int tid = threadIdx.x;
    const int w = tid >> 6, lane = tid & 63;
    const int e0 = blockIdx.x * 64 + w * 16;
    const int rr = lane & 15, kg = lane >> 4;

    // B frag: Wq = W13 rows 128..159
    bf16x8s Bh, Bl;
#pragma unroll
    for (int j = 0; j < 8; j++) {
        const int k = 128 + kg * 8 + j;
        float wv;
        if (rr < 12)       wv = intW[k * 12 + rr];
        else if (rr == 12) wv = impW[k];
        else               wv = 0.f;
        const unsigned short hb = f2bf(wv);
        Bh[j] = (short)hb;
        Bl[j] = (short)f2bf(wv - bf2f(hb));
    }

    // stage relu(ea) as bf16 hi/lo: lane covers edge j=lane>>2, 8 floats at q=(lane&3)*8
    {
        const int j = lane >> 2, q = lane & 3;
        const float4* src = (const float4*)&ea[(size_t)(e0 + j) * 32 + q * 8];
        const float4 f0 = src[0], f1 = src[1];
        const float fv[8] = {fmaxf(f0.x, 0.f), fmaxf(f0.y, 0.f), fmaxf(f0.z, 0.f), fmaxf(f0.w, 0.f),
                             fmaxf(f1.x, 0.f), fmaxf(f1.y, 0.f), fmaxf(f1.z, 0.f), fmaxf(f1.w, 0.f)};
        unsigned long long ph0 = 0, pl0 = 0, ph1 = 0, pl1 = 0;
#pragma unroll
        for (int t = 0; t < 4; t++) {
            const unsigned short hb = f2bf(fv[t]);
            const unsigned short lb = f2bf(fv[t] - bf2f(hb));
            ph0 |= (unsigned long long)hb << (16 * t);
            pl0 |= (unsigned long long)lb << (16 * t);
        }
#pragma unroll
        for (int t = 0; t < 4; t++) {
            const unsigned short hb = f2bf(fv[4 + t]);
            const unsigned short lb = f2bf(fv[4 + t] - bf2f(hb));
            ph1 |= (unsigned long long)hb << (16 * t);
            pl1 |= (unsigned long long)lb << (16 * t);
        }
        *(unsigned long long*)&ehi[w][j * ROWS + q * 8]     = ph0;
        *(unsigned long long*)&ehi[w][j * ROWS + q * 8 + 4] = ph1;
        *(unsigned long long*)&elo[w][j * ROWS + q * 8]     = pl0;
        *(unsigned long long*)&elo[w][j * ROWS + q * 8 + 4] = pl1;
    }
    __syncthreads();

    // MFMA: Q[16 edges][16 cols], K=32
    const int aoff = rr * ROWS + kg * 8;
    const bf16x8s Ah = *(const bf16x8s*)&ehi[w][aoff];
    const bf16x8s Al = *(const bf16x8s*)&elo[w][aoff];
    f32x4 q = {0.f, 0.f, 0.f, 0.f};
    q = __builtin_amdgcn_mfma_f32_16x16x32_bf16(Ah, Bh, q, 0, 0, 0);
    q = __builtin_amdgcn_mfma_f32_16x16x32_bf16(Ah, Bl, q, 0, 0, 0);
    q = __builtin_amdgcn_mfma_f32_16x16x32_bf16(Al, Bh, q, 0, 0, 0);

    // epilogue: col c = rr; rows = kg*4 + r -> edges
    if (rr < 13) {
        const float bv = (rr < 12) ? intb[rr] : impb[0];
#pragma unroll
        for (int r = 0; r < 4; r++) {
            const int e = e0 + kg * 4 + r;
            const int s = ei[e], d = ei[kE + e];
            const float val = q[r] + P[s * 32 + rr] + P[d * 32 + 16 + rr] + bv;
            if (rr < 12) out[(size_t)e * 12 + rr] = val;
            else         out[(size_t)kE * 12 + e] = 1.f / (1.f + __expf(-val));
        }
    }
}

// ---------------- launch ----------------
extern "C" void kernel_launch(void* const* d_in, const int* in_sizes, int n_in,
                              void* d_out, int out_size, void* d_ws, size_t ws_size,
                              hipStream_t stream)
{
    (void)in_sizes; (void)n_in; (void)out_size; (void)ws_size;

    const float* x      = (const float*)d_in[0];
    const int*   ei     = (const int*)d_in[1];
    const float* ea     = (const float*)d_in[2];
    const float* emb_W  = (const float*)d_in[3];
    const float* emb_b  = (const float*)d_in[4];
    const float* g1_Wl  = (const float*)d_in[5];
    const float* g1_bl  = (const float*)d_in[6];
    const float* g1_Wr  = (const float*)d_in[7];
    const float* g1_br  = (const float*)d_in[8];
    const float* g1_We  = (const float*)d_in[9];
    const float* g1_att = (const float*)d_in[10];
    const float* g1_bias= (const float*)d_in[11];
    const float* g2_Wl  = (const float*)d_in[12];
    const float* g2_bl  = (const float*)d_in[13];
    const float* g2_Wr  = (const float*)d_in[14];
    const float* g2_br  = (const float*)d_in[15];
    const float* g2_We  = (const float*)d_in[16];
    const float* g2_att = (const float*)d_in[17];
    const float* g2_bias= (const float*)d_in[18];
    const float* int_W  = (const float*)d_in[19];
    const float* int_b  = (const float*)d_in[20];
    const float* imp_W  = (const float*)d_in[21];
    const float* imp_b  = (const float*)d_in[22];

    char* ws = (char*)d_ws;
    float* eapart  = (float*)(ws + OFF_EAPART);
    float* eamean  = (float*)(ws + OFF_EAMEAN);
    int*   counts  = (int*)  (ws + OFF_COUNTS);
    int*   offs    = (int*)  (ws + OFF_OFFS);
    int*   cursor  = (int*)  (ws + OFF_CURSOR);
    int*   csrsrc  = (int*)  (ws + OFF_CSRSRC);
    int*   csreid  = (int*)  (ws + OFF_CSREID);
    int*   csrdst  = (int*)  (ws + OFF_CSRDST);
    float* pe      = (float*)(ws + OFF_PE);
    float* h_a     = (float*)(ws + OFF_HA);
    float* h_b     = (float*)(ws + OFF_HB);
    float* xl      = (float*)(ws + OFF_XL);
    float* xr      = (float*)(ws + OFF_XR);
    unsigned short* we1h = (unsigned short*)(ws + OFF_WE1H);
    unsigned short* we1l = (unsigned short*)(ws + OFF_WE1L);
    unsigned short* we2h = (unsigned short*)(ws + OFF_WE2H);
    unsigned short* we2l = (unsigned short*)(ws + OFF_WE2L);
    float* P       = pe;                      // reuse pe region after last aggr
    float* outp    = (float*)d_out;

    constexpr int NT = (kTaug + 31) / 32;   // 13282 edge tiles

    // edge_attr mean + We bf16 splits
    ea_colsum_part<<<1024, 256, 0, stream>>>(ea, eapart);
    ea_colsum_final<<<1, 256, 0, stream>>>(eapart, eamean);
    we_split<<<64, 256, 0, stream>>>(g1_We, g2_We, we1h, we1l, we2h, we2l);

    // CSR by destination (self-loops included)
    init_counts<<<(kN + 255) / 256, 256, 0, stream>>>(counts);
    count_edges<<<(kE + 255) / 256, 256, 0, stream>>>(ei, counts);
    scan_kernel<<<1, 1024, 0, stream>>>(counts, offs, cursor);
    scatter_kernel<<<(kE + kN + 255) / 256, 256, 0, stream>>>(ei, cursor, csrsrc, csreid, csrdst);

    // node embedding
    gemm_bias<128, 64, 32><<<(kN + 31) / 32, 256, 0, stream>>>(x, emb_W, emb_b, h_a, kN);

    // ---- GAT layer 1 ----
    gemm_bias<64, 256, 32><<<(kN + 31) / 32, 256, 0, stream>>>(h_a, g1_Wl, g1_bl, xl, kN);
    gemm_bias<64, 256, 32><<<(kN + 31) / 32, 256, 0, stream>>>(h_a, g1_Wr, g1_br, xr, kN);
    edge_logit_kernel<<<NT, 256, 0, stream>>>(xl, xr, ea, eamean, we1h, we1l, g1_att,
                                              csrsrc, csrdst, csreid, pe);
    gat_aggr_kernel<<<kN, 256, 0, stream>>>(xl, pe, csrsrc, offs, g1_bias, h_b);

    // ---- GAT layer 2 ----
    gemm_bias<64, 256, 32><<<(kN + 31) / 32, 256, 0, stream>>>(h_b, g2_Wl, g2_bl, xl, kN);
    gemm_bias<64, 256, 32><<<(kN + 31) / 32, 256, 0, stream>>>(h_b, g2_Wr, g2_br, xr, kN);
    edge_logit_kernel<<<NT, 256, 0, stream>>>(xl, xr, ea, eamean, we2h, we2l, g2_att,
                                              csrsrc, csrdst, csreid, pe);
    gat_aggr_kernel<<<kN, 256, 0, stream>>>(xl, pe, csrsrc, offs, g2_bias, h_a);

    // ---- edge heads (decomposed) ----
    node_head_kernel<<<(kN + 63) / 64, 256, 0, stream>>>(h_a, int_W, imp_W, P);
    edge_out_kernel<<<kE / 64, 256, 0, stream>>>(ea, ei, P, int_W, int_b, imp_W, imp_b, outp);
}